// Round 4
// baseline (57553.931 us; speedup 1.0000x reference)
//
#include <hip/hip_runtime.h>
#include <hip/hip_bf16.h>
#include <math.h>

#define Hn 512
#define En 256
#define Sn 32
#define Bn 1024
#define Tn 32
#define Vn 256
#define G3 1536
#define EHn 768
#define KSTR 520  // kproj LDS row stride (floats): 512+8 pad

// LDS layout (floats)
#define O_KP   0            // kproj [2][32][KSTR] = 33280
#define O_H0   33280        // [2][512]
#define O_H1   34304
#define O_QP   35328
#define O_GIN  36352        // [2][768]
#define O_VA   37888        // [512]
#define O_SCR  38400        // [512] floats (also enc staging in kproj phase)
#define O_SIDX 38912        // [512] ints
#define O_WR   39424        // [2][32] attention weights
#define O_MISC 39488        // lloss[2]
#define O_TOK  39496        // int[2]
#define O_MF   39498        // int[2]
#define LDS_FLOATS 39504
#define LDS_BYTES (LDS_FLOATS * 4)

// dot(fp32 weight row, fp32 LDS vector), K = 4*K4. wrow 16B-aligned.
__device__ __forceinline__ float dotw(const float* __restrict__ wrow,
                                      const float* __restrict__ x, int K4) {
  const float4* wp = (const float4*)wrow;
  float a = 0.f;
  for (int i = 0; i < K4; ++i) {
    const float4 q = wp[i];
    const float* xx = x + (i << 2);
    a = fmaf(q.x, xx[0], a);
    a = fmaf(q.y, xx[1], a);
    a = fmaf(q.z, xx[2], a);
    a = fmaf(q.w, xx[3], a);
  }
  return a;
}

__global__ __launch_bounds__(512, 1) void decoder_persist(
    const float* __restrict__ state, const float* __restrict__ enc,
    const int* __restrict__ target, const float* __restrict__ emb,
    const float* __restrict__ Wa, const float* __restrict__ bWa,
    const float* __restrict__ Ua, const float* __restrict__ bUa,
    const float* __restrict__ Va, const float* __restrict__ bVa,
    const float* __restrict__ Wih0, const float* __restrict__ Whh0,
    const float* __restrict__ bih0, const float* __restrict__ bhh0,
    const float* __restrict__ Wih1, const float* __restrict__ Whh1,
    const float* __restrict__ bih1, const float* __restrict__ bhh1,
    const float* __restrict__ fcW, const float* __restrict__ fcb,
    float* __restrict__ out, float* __restrict__ wsloss, int* __restrict__ wscorrect) {
  extern __shared__ float L[];
  const int tid = threadIdx.x;
  const int b0 = blockIdx.x * 2;  // two batch rows per block

  float* kp = L + O_KP;
  float* h0 = L + O_H0;
  float* h1 = L + O_H1;
  float* qp = L + O_QP;
  float* gin = L + O_GIN;
  float* va = L + O_VA;
  float* scr = L + O_SCR;
  int* sidx = (int*)(L + O_SIDX);
  float* wr = L + O_WR;
  float* lloss = L + O_MISC;
  int* tokb = (int*)(L + O_TOK);
  int* mf = (int*)(L + O_MF);

  // ---- init state / constants ----
  for (int idx = tid; idx < 1024; idx += 512) {
    const int r = idx >> 9, j = idx & 511;
    h0[idx] = state[(size_t)(b0 + r) * Hn + j];
    h1[idx] = state[(size_t)(Bn + b0 + r) * Hn + j];
  }
  va[tid] = Va[tid];
  if (tid == 0) { tokb[0] = 1; tokb[1] = 1; mf[0] = 1; mf[1] = 1; }
  __syncthreads();

  // ---- kproj[r][s][h] = (enc[s][b] . Ua[h]) + bUa[h], fp32, once ----
  for (int r = 0; r < 2; ++r) {
    const int b = b0 + r;
    float acc[32];
#pragma unroll
    for (int s = 0; s < 32; ++s) acc[s] = 0.f;
    for (int kc = 0; kc < Hn; kc += 16) {
      {  // stage enc[s][b][kc..kc+15] -> scr[s*16+k]
        const int s = tid >> 4, k = tid & 15;
        scr[tid] = enc[((size_t)s * Bn + b) * Hn + kc + k];
      }
      __syncthreads();
      const float4* up = (const float4*)(Ua + (size_t)tid * Hn + kc);
      const float4 q0 = up[0], q1 = up[1], q2 = up[2], q3 = up[3];
      const float u[16] = {q0.x, q0.y, q0.z, q0.w, q1.x, q1.y, q1.z, q1.w,
                           q2.x, q2.y, q2.z, q2.w, q3.x, q3.y, q3.z, q3.w};
#pragma unroll
      for (int s = 0; s < 32; ++s) {
        const float* es = scr + s * 16;
#pragma unroll
        for (int k = 0; k < 16; ++k) acc[s] = fmaf(u[k], es[k], acc[s]);
      }
      __syncthreads();
    }
    const float bu = bUa[tid];
#pragma unroll
    for (int s = 0; s < 32; ++s) kp[(r * 32 + s) * KSTR + tid] = acc[s] + bu;
  }
  __syncthreads();

  float run_loss = 0.f;  // thread 0 only

  for (int t = 0; t < Tn; ++t) {
    // ---- qp = Wa @ h1 + bWa ----
    for (int idx = tid; idx < 1024; idx += 512) {
      const int r = idx >> 9, h = idx & 511;
      qp[idx] = dotw(Wa + (size_t)h * Hn, h1 + r * 512, Hn / 4) + bWa[h];
    }
    __syncthreads();
    // ---- e partials: pair p=(r,s) gets 8 threads; h = sub + 8*i ----
    {
      const int p = tid >> 3, sub = tid & 7;
      const int r = p >> 5;
      const float* kpr = kp + p * KSTR;
      const float* qpr = qp + r * 512;
      float sum = 0.f;
#pragma unroll
      for (int i = 0; i < 64; ++i) {
        const int h = sub + (i << 3);
        sum = fmaf(va[h], tanhf(qpr[h] + kpr[h]), sum);
      }
      scr[tid] = sum;
    }
    __syncthreads();
    // ---- softmax over s (wave 0: lanes 0-31 row0, 32-63 row1) ----
    if (tid < 64) {
      float e = 0.f;
#pragma unroll
      for (int u = 0; u < 8; ++u) e += scr[tid * 8 + u];
      e += bVa[0];
      float m = e;
#pragma unroll
      for (int off = 16; off; off >>= 1) m = fmaxf(m, __shfl_xor(m, off));
      const float ex = expf(e - m);
      float ss = ex;
#pragma unroll
      for (int off = 16; off; off >>= 1) ss += __shfl_xor(ss, off);
      const float w = ex / ss;
      wr[tid] = w;
      const int r = tid >> 5, s = tid & 31;
      out[(size_t)Bn * Tn + (size_t)t * Bn * Sn + (size_t)(b0 + r) * Sn + s] = w;
    }
    __syncthreads();
    // ---- context + relu(emb[tok]) -> gin ----
    for (int idx = tid; idx < 1024; idx += 512) {
      const int r = idx >> 9, h = idx & 511;
      const float* w = wr + r * 32;
      float c = 0.f;
#pragma unroll
      for (int s = 0; s < Sn; ++s)
        c = fmaf(w[s], enc[((size_t)s * Bn + (b0 + r)) * Hn + h], c);
      gin[r * EHn + En + h] = c;
    }
    {
      const int r = tid >> 8, j = tid & 255;
      gin[r * EHn + j] = fmaxf(emb[(size_t)tokb[r] * En + j], 0.f);
    }
    __syncthreads();
    // ---- GRU layer 0: x = gin (K=768), state h0 ----
    {
      float hn[2];
#pragma unroll
      for (int pass = 0; pass < 2; ++pass) {
        const int idx = tid + pass * 512;
        const int r = idx >> 9, j = idx & 511;
        const float* x = gin + r * EHn;
        const float* hh = h0 + r * 512;
        const float ir = dotw(Wih0 + (size_t)j * EHn, x, EHn / 4) + bih0[j];
        const float iz = dotw(Wih0 + (size_t)(j + 512) * EHn, x, EHn / 4) + bih0[j + 512];
        const float in_ = dotw(Wih0 + (size_t)(j + 1024) * EHn, x, EHn / 4) + bih0[j + 1024];
        const float hr = dotw(Whh0 + (size_t)j * Hn, hh, Hn / 4) + bhh0[j];
        const float hz = dotw(Whh0 + (size_t)(j + 512) * Hn, hh, Hn / 4) + bhh0[j + 512];
        const float hnn = dotw(Whh0 + (size_t)(j + 1024) * Hn, hh, Hn / 4) + bhh0[j + 1024];
        const float rg = 1.f / (1.f + expf(-(ir + hr)));
        const float zg = 1.f / (1.f + expf(-(iz + hz)));
        const float ng = tanhf(in_ + rg * hnn);
        hn[pass] = (1.f - zg) * ng + zg * hh[j];
      }
      __syncthreads();
      h0[tid] = hn[0];
      h0[tid + 512] = hn[1];
      __syncthreads();
    }
    // ---- GRU layer 1: x = h0 (K=512), state h1 ----
    {
      float hn[2];
#pragma unroll
      for (int pass = 0; pass < 2; ++pass) {
        const int idx = tid + pass * 512;
        const int r = idx >> 9, j = idx & 511;
        const float* x = h0 + r * 512;
        const float* hh = h1 + r * 512;
        const float ir = dotw(Wih1 + (size_t)j * Hn, x, Hn / 4) + bih1[j];
        const float iz = dotw(Wih1 + (size_t)(j + 512) * Hn, x, Hn / 4) + bih1[j + 512];
        const float in_ = dotw(Wih1 + (size_t)(j + 1024) * Hn, x, Hn / 4) + bih1[j + 1024];
        const float hr = dotw(Whh1 + (size_t)j * Hn, hh, Hn / 4) + bhh1[j];
        const float hz = dotw(Whh1 + (size_t)(j + 512) * Hn, hh, Hn / 4) + bhh1[j + 512];
        const float hnn = dotw(Whh1 + (size_t)(j + 1024) * Hn, hh, Hn / 4) + bhh1[j + 1024];
        const float rg = 1.f / (1.f + expf(-(ir + hr)));
        const float zg = 1.f / (1.f + expf(-(iz + hz)));
        const float ng = tanhf(in_ + rg * hnn);
        hn[pass] = (1.f - zg) * ng + zg * hh[j];
      }
      __syncthreads();
      h1[tid] = hn[0];
      h1[tid + 512] = hn[1];
      __syncthreads();
    }
    // ---- logits + argmax + log_softmax + loss + next token ----
    {
      const int r = tid >> 8, v = tid & 255;
      const int b = b0 + r;
      const float l = dotw(fcW + (size_t)v * Hn, h1 + r * 512, Hn / 4) + fcb[v];
      scr[tid] = l;
      sidx[tid] = v;
      __syncthreads();
      for (int off = 128; off; off >>= 1) {
        if ((tid & 255) < off) {
          const float o = scr[tid + off];
          const int oi = sidx[tid + off];
          if (o > scr[tid] || (o == scr[tid] && oi < sidx[tid])) {
            scr[tid] = o; sidx[tid] = oi;
          }
        }
        __syncthreads();
      }
      const float mx = scr[r << 8];
      const int am = sidx[r << 8];
      __syncthreads();
      scr[tid] = expf(l - mx);
      __syncthreads();
      for (int off = 128; off; off >>= 1) {
        if ((tid & 255) < off) scr[tid] += scr[tid + off];
        __syncthreads();
      }
      const float lz = logf(scr[r << 8]);
      const int tgt = target[(size_t)b * Tn + t];
      if (v == tgt) lloss[r] = -(l - mx - lz) * (1.f / 1024.f);
      if (v == 0) {
        tokb[r] = am;
        if (am != tgt) mf[r] = 0;
        out[(size_t)b * Tn + t] = (float)am;
      }
      __syncthreads();
      if (tid == 0) run_loss += lloss[0] + lloss[1];
    }
  }

  if (tid == 0) {
    atomicAdd(wsloss, run_loss);
    atomicAdd(wscorrect, mf[0] + mf[1]);
  }
}

__global__ void ws_init(float* wsloss, int* wscorrect) {
  wsloss[0] = 0.f;
  wscorrect[0] = 0;
}

__global__ void finisher(const float* __restrict__ wsloss,
                         const int* __restrict__ wscorrect, float* __restrict__ out) {
  const size_t base = (size_t)Bn * Tn + (size_t)Tn * Bn * Sn;
  out[base] = wsloss[0];
  out[base + 1] = (float)wscorrect[0];
}

extern "C" void kernel_launch(void* const* d_in, const int* in_sizes, int n_in,
                              void* d_out, int out_size, void* d_ws, size_t ws_size,
                              hipStream_t stream) {
  const float* state = (const float*)d_in[0];
  const float* enc = (const float*)d_in[1];
  const int* target = (const int*)d_in[2];
  const float* emb = (const float*)d_in[3];
  const float* Wa = (const float*)d_in[4];
  const float* bWa = (const float*)d_in[5];
  const float* Ua = (const float*)d_in[6];
  const float* bUa = (const float*)d_in[7];
  const float* Va = (const float*)d_in[8];
  const float* bVa = (const float*)d_in[9];
  const float* Wih0 = (const float*)d_in[10];
  const float* Whh0 = (const float*)d_in[11];
  const float* bih0 = (const float*)d_in[12];
  const float* bhh0 = (const float*)d_in[13];
  const float* Wih1 = (const float*)d_in[14];
  const float* Whh1 = (const float*)d_in[15];
  const float* bih1 = (const float*)d_in[16];
  const float* bhh1 = (const float*)d_in[17];
  const float* fcW = (const float*)d_in[18];
  const float* fcb = (const float*)d_in[19];
  float* out = (float*)d_out;

  float* wsloss = (float*)d_ws;     // 4 bytes
  int* wscorrect = (int*)d_ws + 1;  // 4 bytes (total ws use: 8 bytes)

  hipFuncSetAttribute((const void*)decoder_persist,
                      hipFuncAttributeMaxDynamicSharedMemorySize, LDS_BYTES);

  ws_init<<<1, 1, 0, stream>>>(wsloss, wscorrect);
  decoder_persist<<<Bn / 2, 512, LDS_BYTES, stream>>>(
      state, enc, target, emb, Wa, bWa, Ua, bUa, Va, bVa, Wih0, Whh0, bih0, bhh0,
      Wih1, Whh1, bih1, bhh1, fcW, fcb, out, wsloss, wscorrect);
  finisher<<<1, 1, 0, stream>>>(wsloss, wscorrect, out);
}

// Round 5
// 17896.423 us; speedup vs baseline: 3.2159x; 3.2159x over previous
//
#include <hip/hip_runtime.h>
#include <math.h>

#define Hn 512
#define En 256
#define Sn 32
#define Bn 1024
#define Tn 32
#define Vn 256
#define G3 1536
#define EHn 768

// ======================= kproj GEMM (Path A precompute) =======================
// C(M,N) = A(M,K) @ W(N,K)^T + bias(N), fp32. 64x64 tile, BK=16, 256 thr, 4x4 micro.
__global__ __launch_bounds__(256) void gemm_bias(const float* __restrict__ A,
                                                 const float* __restrict__ Wt,
                                                 const float* __restrict__ bias,
                                                 float* __restrict__ C,
                                                 int M, int N, int K) {
  __shared__ float As[16][68];
  __shared__ float Ws[16][68];
  const int bm = blockIdx.y * 64;
  const int bn = blockIdx.x * 64;
  const int tid = threadIdx.x;
  const int tx = tid & 15;
  const int ty = tid >> 4;
  const int kk = tid & 15;
  const int r0 = tid >> 4;
  float acc[4][4] = {};
  for (int k0 = 0; k0 < K; k0 += 16) {
#pragma unroll
    for (int i = 0; i < 4; ++i) {
      const int m = r0 + (i << 4);
      As[kk][m] = A[(size_t)(bm + m) * K + (k0 + kk)];
      Ws[kk][m] = Wt[(size_t)(bn + m) * K + (k0 + kk)];
    }
    __syncthreads();
#pragma unroll
    for (int k = 0; k < 16; ++k) {
      const float4 a4 = *(const float4*)&As[k][ty * 4];
      const float4 w4 = *(const float4*)&Ws[k][tx * 4];
      const float av[4] = {a4.x, a4.y, a4.z, a4.w};
      const float wv[4] = {w4.x, w4.y, w4.z, w4.w};
#pragma unroll
      for (int i = 0; i < 4; ++i)
#pragma unroll
        for (int j = 0; j < 4; ++j) acc[i][j] = fmaf(av[i], wv[j], acc[i][j]);
    }
    __syncthreads();
  }
#pragma unroll
  for (int i = 0; i < 4; ++i) {
    const size_t m = (size_t)bm + ty * 4 + i;
    float* crow = C + m * N + bn + tx * 4;
#pragma unroll
    for (int j = 0; j < 4; ++j) crow[j] = acc[i][j] + bias[bn + tx * 4 + j];
  }
}

// ======================= Path A: R=4 persistent decoder =======================
// One weight float4 load feeds 4 batch rows (activations broadcast from LDS).
__device__ __forceinline__ void gru_layer4(int j, const float* __restrict__ x,
                                           int xstride, int K,
                                           float* __restrict__ h,  // LDS [4][Hn]
                                           const float* __restrict__ Wih,
                                           const float* __restrict__ Whh,
                                           const float* __restrict__ bih,
                                           const float* __restrict__ bhh) {
  float ai0[4] = {}, ai1[4] = {}, ai2[4] = {};
  {
    const float4* w0 = (const float4*)(Wih + (size_t)j * K);
    const float4* w1 = (const float4*)(Wih + (size_t)(j + 512) * K);
    const float4* w2 = (const float4*)(Wih + (size_t)(j + 1024) * K);
    for (int i = 0; i < K / 4; ++i) {
      const float4 a = w0[i], b = w1[i], c = w2[i];
#pragma unroll
      for (int r = 0; r < 4; ++r) {
        const float4 xv = ((const float4*)(x + r * xstride))[i];
        ai0[r] = fmaf(a.x, xv.x, ai0[r]); ai0[r] = fmaf(a.y, xv.y, ai0[r]);
        ai0[r] = fmaf(a.z, xv.z, ai0[r]); ai0[r] = fmaf(a.w, xv.w, ai0[r]);
        ai1[r] = fmaf(b.x, xv.x, ai1[r]); ai1[r] = fmaf(b.y, xv.y, ai1[r]);
        ai1[r] = fmaf(b.z, xv.z, ai1[r]); ai1[r] = fmaf(b.w, xv.w, ai1[r]);
        ai2[r] = fmaf(c.x, xv.x, ai2[r]); ai2[r] = fmaf(c.y, xv.y, ai2[r]);
        ai2[r] = fmaf(c.z, xv.z, ai2[r]); ai2[r] = fmaf(c.w, xv.w, ai2[r]);
      }
    }
  }
  float ah0[4] = {}, ah1[4] = {}, ah2[4] = {};
  {
    const float4* w0 = (const float4*)(Whh + (size_t)j * Hn);
    const float4* w1 = (const float4*)(Whh + (size_t)(j + 512) * Hn);
    const float4* w2 = (const float4*)(Whh + (size_t)(j + 1024) * Hn);
    for (int i = 0; i < Hn / 4; ++i) {
      const float4 a = w0[i], b = w1[i], c = w2[i];
#pragma unroll
      for (int r = 0; r < 4; ++r) {
        const float4 xv = ((const float4*)(h + r * Hn))[i];
        ah0[r] = fmaf(a.x, xv.x, ah0[r]); ah0[r] = fmaf(a.y, xv.y, ah0[r]);
        ah0[r] = fmaf(a.z, xv.z, ah0[r]); ah0[r] = fmaf(a.w, xv.w, ah0[r]);
        ah1[r] = fmaf(b.x, xv.x, ah1[r]); ah1[r] = fmaf(b.y, xv.y, ah1[r]);
        ah1[r] = fmaf(b.z, xv.z, ah1[r]); ah1[r] = fmaf(b.w, xv.w, ah1[r]);
        ah2[r] = fmaf(c.x, xv.x, ah2[r]); ah2[r] = fmaf(c.y, xv.y, ah2[r]);
        ah2[r] = fmaf(c.z, xv.z, ah2[r]); ah2[r] = fmaf(c.w, xv.w, ah2[r]);
      }
    }
  }
  const float bi0 = bih[j], bi1 = bih[j + 512], bi2 = bih[j + 1024];
  const float bh0 = bhh[j], bh1 = bhh[j + 512], bh2 = bhh[j + 1024];
  float hn[4];
#pragma unroll
  for (int r = 0; r < 4; ++r) {
    const float ir = ai0[r] + bi0, iz = ai1[r] + bi1, in_ = ai2[r] + bi2;
    const float hr = ah0[r] + bh0, hz = ah1[r] + bh1, hnn = ah2[r] + bh2;
    const float rg = 1.f / (1.f + expf(-(ir + hr)));
    const float zg = 1.f / (1.f + expf(-(iz + hz)));
    const float ng = tanhf(in_ + rg * hnn);
    hn[r] = (1.f - zg) * ng + zg * h[r * Hn + j];
  }
  __syncthreads();
#pragma unroll
  for (int r = 0; r < 4; ++r) h[r * Hn + j] = hn[r];
  __syncthreads();
}

__global__ __launch_bounds__(512, 1) void decoder_r4(
    const float* __restrict__ state, const float* __restrict__ enc,
    const int* __restrict__ target, const float* __restrict__ emb,
    const float* __restrict__ Wa, const float* __restrict__ bWa,
    const float* __restrict__ Va, const float* __restrict__ bVa,
    const float* __restrict__ Wih0, const float* __restrict__ Whh0,
    const float* __restrict__ bih0, const float* __restrict__ bhh0,
    const float* __restrict__ Wih1, const float* __restrict__ Whh1,
    const float* __restrict__ bih1, const float* __restrict__ bhh1,
    const float* __restrict__ fcW, const float* __restrict__ fcb,
    const float* __restrict__ kproj, float* __restrict__ out,
    float* __restrict__ wsloss, int* __restrict__ wscorrect) {
  __shared__ float h0s[4 * Hn], h1s[4 * Hn], qps[4 * Hn], gins[4 * EHn], vas[Hn];
  __shared__ float red[1024], lg[1024];
  __shared__ int ridx[1024];
  __shared__ float wrs[4 * Sn];
  __shared__ float mxv[4], lzv[4], llv[4];
  __shared__ int amv[4], tgv[4], tokb[4], mfs[4];

  const int tid = threadIdx.x;
  const int b0 = blockIdx.x * 4;

  for (int i = tid; i < 4 * Hn; i += 512) {
    const int r = i >> 9, j = i & 511;
    h0s[i] = state[(size_t)(b0 + r) * Hn + j];
    h1s[i] = state[(size_t)(Bn + b0 + r) * Hn + j];
  }
  vas[tid] = Va[tid];
  if (tid < 4) { tokb[tid] = 1; mfs[tid] = 1; llv[tid] = 0.f; }
  __syncthreads();

  float run_loss = 0.f;  // tid 0 only

  for (int t = 0; t < Tn; ++t) {
    // ---- qp = h1 @ Wa^T + bWa (weight row shared across 4 rows) ----
    {
      const int h = tid;
      const float4* w4 = (const float4*)(Wa + (size_t)h * Hn);
      float a0 = 0.f, a1 = 0.f, a2 = 0.f, a3 = 0.f;
      for (int i = 0; i < Hn / 4; ++i) {
        const float4 w = w4[i];
        const float4 x0 = ((const float4*)(h1s))[i];
        const float4 x1 = ((const float4*)(h1s + Hn))[i];
        const float4 x2 = ((const float4*)(h1s + 2 * Hn))[i];
        const float4 x3 = ((const float4*)(h1s + 3 * Hn))[i];
        a0 = fmaf(w.x, x0.x, a0); a0 = fmaf(w.y, x0.y, a0);
        a0 = fmaf(w.z, x0.z, a0); a0 = fmaf(w.w, x0.w, a0);
        a1 = fmaf(w.x, x1.x, a1); a1 = fmaf(w.y, x1.y, a1);
        a1 = fmaf(w.z, x1.z, a1); a1 = fmaf(w.w, x1.w, a1);
        a2 = fmaf(w.x, x2.x, a2); a2 = fmaf(w.y, x2.y, a2);
        a2 = fmaf(w.z, x2.z, a2); a2 = fmaf(w.w, x2.w, a2);
        a3 = fmaf(w.x, x3.x, a3); a3 = fmaf(w.y, x3.y, a3);
        a3 = fmaf(w.z, x3.z, a3); a3 = fmaf(w.w, x3.w, a3);
      }
      const float bb = bWa[h];
      qps[h] = a0 + bb; qps[Hn + h] = a1 + bb;
      qps[2 * Hn + h] = a2 + bb; qps[3 * Hn + h] = a3 + bb;
    }
    __syncthreads();
    // ---- e: 4 threads per (r,s) pair; kproj streamed from global ----
    {
      const int p = tid >> 2, q = tid & 3;  // p = r*32+s
      const int r = p >> 5, s = p & 31;
      const float4* kp4 = (const float4*)(kproj + ((size_t)s * Bn + (b0 + r)) * Hn);
      const float4* qp4 = (const float4*)(qps + r * Hn);
      const float4* va4 = (const float4*)vas;
      float partial = 0.f;
      for (int i = 0; i < 32; ++i) {
        const int f = q + (i << 2);
        const float4 k4 = kp4[f], q4 = qp4[f], v4 = va4[f];
        partial += v4.x * tanhf(q4.x + k4.x);
        partial += v4.y * tanhf(q4.y + k4.y);
        partial += v4.z * tanhf(q4.z + k4.z);
        partial += v4.w * tanhf(q4.w + k4.w);
      }
      red[tid] = partial;
    }
    __syncthreads();
    if (tid < 128) {
      float e = red[tid * 4] + red[tid * 4 + 1] + red[tid * 4 + 2] + red[tid * 4 + 3] + bVa[0];
      float m = e;
#pragma unroll
      for (int off = 16; off; off >>= 1) m = fmaxf(m, __shfl_xor(m, off));
      const float ex = expf(e - m);
      float ss = ex;
#pragma unroll
      for (int off = 16; off; off >>= 1) ss += __shfl_xor(ss, off);
      const float w = ex / ss;
      const int r = tid >> 5, s = tid & 31;
      wrs[tid] = w;
      out[(size_t)(Bn * Tn) + (size_t)t * (Bn * Sn) + (size_t)(b0 + r) * Sn + s] = w;
    }
    __syncthreads();
    // ---- context (coalesced enc reads) + relu(emb[tok]) -> gin ----
    {
      const int h = tid;
      float c0 = 0.f, c1 = 0.f, c2 = 0.f, c3 = 0.f;
      for (int s = 0; s < Sn; ++s) {
        const size_t base = ((size_t)s * Bn + b0) * Hn + h;
        c0 = fmaf(wrs[s], enc[base], c0);
        c1 = fmaf(wrs[32 + s], enc[base + Hn], c1);
        c2 = fmaf(wrs[64 + s], enc[base + 2 * Hn], c2);
        c3 = fmaf(wrs[96 + s], enc[base + 3 * Hn], c3);
      }
      gins[En + h] = c0; gins[EHn + En + h] = c1;
      gins[2 * EHn + En + h] = c2; gins[3 * EHn + En + h] = c3;
    }
    for (int i = tid; i < 4 * En; i += 512) {
      const int r = i >> 8, j = i & 255;
      gins[r * EHn + j] = fmaxf(emb[(size_t)tokb[r] * En + j], 0.f);
    }
    __syncthreads();
    // ---- GRU layers ----
    gru_layer4(tid, gins, EHn, EHn, h0s, Wih0, Whh0, bih0, bhh0);
    gru_layer4(tid, h0s, Hn, Hn, h1s, Wih1, Whh1, bih1, bhh1);
    // ---- fc: thread does v for rows (rA, rA+2); weight row loaded once ----
    {
      const int v = tid & 255;
      const int rA = tid >> 8, rB = rA + 2;
      const float4* w4 = (const float4*)(fcW + (size_t)v * Hn);
      const float4* xA = (const float4*)(h1s + rA * Hn);
      const float4* xB = (const float4*)(h1s + rB * Hn);
      float aA = 0.f, aB = 0.f;
      for (int i = 0; i < Hn / 4; ++i) {
        const float4 w = w4[i];
        const float4 a = xA[i], b = xB[i];
        aA = fmaf(w.x, a.x, aA); aA = fmaf(w.y, a.y, aA);
        aA = fmaf(w.z, a.z, aA); aA = fmaf(w.w, a.w, aA);
        aB = fmaf(w.x, b.x, aB); aB = fmaf(w.y, b.y, aB);
        aB = fmaf(w.z, b.z, aB); aB = fmaf(w.w, b.w, aB);
      }
      const float fb = fcb[v];
      const float lA = aA + fb, lB = aB + fb;
      lg[rA * 256 + v] = lA; red[rA * 256 + v] = lA; ridx[rA * 256 + v] = v;
      lg[rB * 256 + v] = lB; red[rB * 256 + v] = lB; ridx[rB * 256 + v] = v;
    }
    __syncthreads();
    // argmax (first-max tie-break) over each 256-segment
    for (int off = 128; off; off >>= 1) {
#pragma unroll
      for (int half = 0; half < 2; ++half) {
        const int u = tid + half * 512;
        if ((u & 255) < off) {
          const int u2 = u + off;
          const float o = red[u2]; const int oi = ridx[u2];
          if (o > red[u] || (o == red[u] && oi < ridx[u])) { red[u] = o; ridx[u] = oi; }
        }
      }
      __syncthreads();
    }
    if (tid < 4) {
      mxv[tid] = red[tid * 256];
      amv[tid] = ridx[tid * 256];
      tgv[tid] = target[(size_t)(b0 + tid) * Tn + t];
    }
    __syncthreads();
#pragma unroll
    for (int half = 0; half < 2; ++half) {
      const int u = tid + half * 512;
      red[u] = expf(lg[u] - mxv[u >> 8]);
    }
    __syncthreads();
    for (int off = 128; off; off >>= 1) {
#pragma unroll
      for (int half = 0; half < 2; ++half) {
        const int u = tid + half * 512;
        if ((u & 255) < off) red[u] += red[u + off];
      }
      __syncthreads();
    }
    if (tid < 4) {
      const int r = tid;
      lzv[r] = logf(red[r * 256]);
      tokb[r] = amv[r];
      if (amv[r] != tgv[r]) mfs[r] = 0;
      out[(size_t)(b0 + r) * Tn + t] = (float)amv[r];
    }
    __syncthreads();
#pragma unroll
    for (int half = 0; half < 2; ++half) {
      const int u = tid + half * 512;
      const int r = u >> 8, v = u & 255;
      if (v == tgv[r]) llv[r] = -(lg[u] - mxv[r] - lzv[r]) * (1.f / 1024.f);
    }
    __syncthreads();
    if (tid == 0) run_loss += llv[0] + llv[1] + llv[2] + llv[3];
    __syncthreads();
  }

  if (tid == 0) {
    atomicAdd(wsloss, run_loss);
    atomicAdd(wscorrect, mfs[0] + mfs[1] + mfs[2] + mfs[3]);
  }
}

// ======================= Path B: fallback (Round-4, R=2, LDS kproj) ===========
#define KSTR 520
#define O_KP   0
#define O_H0   33280
#define O_H1   34304
#define O_QP   35328
#define O_GIN  36352
#define O_VA   37888
#define O_SCR  38400
#define O_SIDX 38912
#define O_WR   39424
#define O_MISC 39488
#define O_TOK  39496
#define O_MF   39498
#define LDS_FLOATS 39504
#define LDS_BYTES (LDS_FLOATS * 4)

__device__ __forceinline__ float dotw(const float* __restrict__ wrow,
                                      const float* __restrict__ x, int K4) {
  const float4* wp = (const float4*)wrow;
  float a = 0.f;
  for (int i = 0; i < K4; ++i) {
    const float4 q = wp[i];
    const float* xx = x + (i << 2);
    a = fmaf(q.x, xx[0], a); a = fmaf(q.y, xx[1], a);
    a = fmaf(q.z, xx[2], a); a = fmaf(q.w, xx[3], a);
  }
  return a;
}

__global__ __launch_bounds__(512, 1) void decoder_persist(
    const float* __restrict__ state, const float* __restrict__ enc,
    const int* __restrict__ target, const float* __restrict__ emb,
    const float* __restrict__ Wa, const float* __restrict__ bWa,
    const float* __restrict__ Ua, const float* __restrict__ bUa,
    const float* __restrict__ Va, const float* __restrict__ bVa,
    const float* __restrict__ Wih0, const float* __restrict__ Whh0,
    const float* __restrict__ bih0, const float* __restrict__ bhh0,
    const float* __restrict__ Wih1, const float* __restrict__ Whh1,
    const float* __restrict__ bih1, const float* __restrict__ bhh1,
    const float* __restrict__ fcW, const float* __restrict__ fcb,
    float* __restrict__ out, float* __restrict__ wsloss, int* __restrict__ wscorrect) {
  extern __shared__ float L[];
  const int tid = threadIdx.x;
  const int b0 = blockIdx.x * 2;
  float* kp = L + O_KP; float* h0 = L + O_H0; float* h1 = L + O_H1;
  float* qp = L + O_QP; float* gin = L + O_GIN; float* va = L + O_VA;
  float* scr = L + O_SCR; int* sidx = (int*)(L + O_SIDX); float* wr = L + O_WR;
  float* lloss = L + O_MISC; int* tokb = (int*)(L + O_TOK); int* mf = (int*)(L + O_MF);

  for (int idx = tid; idx < 1024; idx += 512) {
    const int r = idx >> 9, j = idx & 511;
    h0[idx] = state[(size_t)(b0 + r) * Hn + j];
    h1[idx] = state[(size_t)(Bn + b0 + r) * Hn + j];
  }
  va[tid] = Va[tid];
  if (tid == 0) { tokb[0] = 1; tokb[1] = 1; mf[0] = 1; mf[1] = 1; }
  __syncthreads();

  for (int r = 0; r < 2; ++r) {
    const int b = b0 + r;
    float acc[32];
#pragma unroll
    for (int s = 0; s < 32; ++s) acc[s] = 0.f;
    for (int kc = 0; kc < Hn; kc += 16) {
      { const int s = tid >> 4, k = tid & 15;
        scr[tid] = enc[((size_t)s * Bn + b) * Hn + kc + k]; }
      __syncthreads();
      const float4* up = (const float4*)(Ua + (size_t)tid * Hn + kc);
      const float4 q0 = up[0], q1 = up[1], q2 = up[2], q3 = up[3];
      const float u[16] = {q0.x, q0.y, q0.z, q0.w, q1.x, q1.y, q1.z, q1.w,
                           q2.x, q2.y, q2.z, q2.w, q3.x, q3.y, q3.z, q3.w};
#pragma unroll
      for (int s = 0; s < 32; ++s) {
        const float* es = scr + s * 16;
#pragma unroll
        for (int k = 0; k < 16; ++k) acc[s] = fmaf(u[k], es[k], acc[s]);
      }
      __syncthreads();
    }
    const float bu = bUa[tid];
#pragma unroll
    for (int s = 0; s < 32; ++s) kp[(r * 32 + s) * KSTR + tid] = acc[s] + bu;
  }
  __syncthreads();

  float run_loss = 0.f;
  for (int t = 0; t < Tn; ++t) {
    for (int idx = tid; idx < 1024; idx += 512) {
      const int r = idx >> 9, h = idx & 511;
      qp[idx] = dotw(Wa + (size_t)h * Hn, h1 + r * 512, Hn / 4) + bWa[h];
    }
    __syncthreads();
    {
      const int p = tid >> 3, sub = tid & 7;
      const int r = p >> 5;
      const float* kpr = kp + p * KSTR;
      const float* qpr = qp + r * 512;
      float sum = 0.f;
#pragma unroll
      for (int i = 0; i < 64; ++i) {
        const int h = sub + (i << 3);
        sum = fmaf(va[h], tanhf(qpr[h] + kpr[h]), sum);
      }
      scr[tid] = sum;
    }
    __syncthreads();
    if (tid < 64) {
      float e = 0.f;
#pragma unroll
      for (int u = 0; u < 8; ++u) e += scr[tid * 8 + u];
      e += bVa[0];
      float m = e;
#pragma unroll
      for (int off = 16; off; off >>= 1) m = fmaxf(m, __shfl_xor(m, off));
      const float ex = expf(e - m);
      float ss = ex;
#pragma unroll
      for (int off = 16; off; off >>= 1) ss += __shfl_xor(ss, off);
      const float w = ex / ss;
      wr[tid] = w;
      const int r = tid >> 5, s = tid & 31;
      out[(size_t)Bn * Tn + (size_t)t * Bn * Sn + (size_t)(b0 + r) * Sn + s] = w;
    }
    __syncthreads();
    for (int idx = tid; idx < 1024; idx += 512) {
      const int r = idx >> 9, h = idx & 511;
      const float* w = wr + r * 32;
      float c = 0.f;
#pragma unroll
      for (int s = 0; s < Sn; ++s)
        c = fmaf(w[s], enc[((size_t)s * Bn + (b0 + r)) * Hn + h], c);
      gin[r * EHn + En + h] = c;
    }
    { const int r = tid >> 8, j = tid & 255;
      gin[r * EHn + j] = fmaxf(emb[(size_t)tokb[r] * En + j], 0.f); }
    __syncthreads();
    {
      float hn[2];
#pragma unroll
      for (int pass = 0; pass < 2; ++pass) {
        const int idx = tid + pass * 512;
        const int r = idx >> 9, j = idx & 511;
        const float* x = gin + r * EHn;
        const float* hh = h0 + r * 512;
        const float ir = dotw(Wih0 + (size_t)j * EHn, x, EHn / 4) + bih0[j];
        const float iz = dotw(Wih0 + (size_t)(j + 512) * EHn, x, EHn / 4) + bih0[j + 512];
        const float in_ = dotw(Wih0 + (size_t)(j + 1024) * EHn, x, EHn / 4) + bih0[j + 1024];
        const float hr = dotw(Whh0 + (size_t)j * Hn, hh, Hn / 4) + bhh0[j];
        const float hz = dotw(Whh0 + (size_t)(j + 512) * Hn, hh, Hn / 4) + bhh0[j + 512];
        const float hnn = dotw(Whh0 + (size_t)(j + 1024) * Hn, hh, Hn / 4) + bhh0[j + 1024];
        const float rg = 1.f / (1.f + expf(-(ir + hr)));
        const float zg = 1.f / (1.f + expf(-(iz + hz)));
        const float ng = tanhf(in_ + rg * hnn);
        hn[pass] = (1.f - zg) * ng + zg * hh[j];
      }
      __syncthreads();
      h0[tid] = hn[0]; h0[tid + 512] = hn[1];
      __syncthreads();
    }
    {
      float hn[2];
#pragma unroll
      for (int pass = 0; pass < 2; ++pass) {
        const int idx = tid + pass * 512;
        const int r = idx >> 9, j = idx & 511;
        const float* x = h0 + r * 512;
        const float* hh = h1 + r * 512;
        const float ir = dotw(Wih1 + (size_t)j * Hn, x, Hn / 4) + bih1[j];
        const float iz = dotw(Wih1 + (size_t)(j + 512) * Hn, x, Hn / 4) + bih1[j + 512];
        const float in_ = dotw(Wih1 + (size_t)(j + 1024) * Hn, x, Hn / 4) + bih1[j + 1024];
        const float hr = dotw(Whh1 + (size_t)j * Hn, hh, Hn / 4) + bhh1[j];
        const float hz = dotw(Whh1 + (size_t)(j + 512) * Hn, hh, Hn / 4) + bhh1[j + 512];
        const float hnn = dotw(Whh1 + (size_t)(j + 1024) * Hn, hh, Hn / 4) + bhh1[j + 1024];
        const float rg = 1.f / (1.f + expf(-(ir + hr)));
        const float zg = 1.f / (1.f + expf(-(iz + hz)));
        const float ng = tanhf(in_ + rg * hnn);
        hn[pass] = (1.f - zg) * ng + zg * hh[j];
      }
      __syncthreads();
      h1[tid] = hn[0]; h1[tid + 512] = hn[1];
      __syncthreads();
    }
    {
      const int r = tid >> 8, v = tid & 255;
      const int b = b0 + r;
      const float l = dotw(fcW + (size_t)v * Hn, h1 + r * 512, Hn / 4) + fcb[v];
      scr[tid] = l; sidx[tid] = v;
      __syncthreads();
      for (int off = 128; off; off >>= 1) {
        if ((tid & 255) < off) {
          const float o = scr[tid + off]; const int oi = sidx[tid + off];
          if (o > scr[tid] || (o == scr[tid] && oi < sidx[tid])) { scr[tid] = o; sidx[tid] = oi; }
        }
        __syncthreads();
      }
      const float mx = scr[r << 8]; const int am = sidx[r << 8];
      __syncthreads();
      scr[tid] = expf(l - mx);
      __syncthreads();
      for (int off = 128; off; off >>= 1) {
        if ((tid & 255) < off) scr[tid] += scr[tid + off];
        __syncthreads();
      }
      const float lz = logf(scr[r << 8]);
      const int tgt = target[(size_t)b * Tn + t];
      if (v == tgt) lloss[r] = -(l - mx - lz) * (1.f / 1024.f);
      if (v == 0) {
        tokb[r] = am;
        if (am != tgt) mf[r] = 0;
        out[(size_t)b * Tn + t] = (float)am;
      }
      __syncthreads();
      if (tid == 0) run_loss += lloss[0] + lloss[1];
    }
  }
  if (tid == 0) {
    atomicAdd(wsloss, run_loss);
    atomicAdd(wscorrect, mf[0] + mf[1]);
  }
}

// ======================= common epilogue =======================
__global__ void ws_init(float* wsloss, int* wscorrect) {
  wsloss[0] = 0.f;
  wscorrect[0] = 0;
}

__global__ void finisher(const float* __restrict__ wsloss,
                         const int* __restrict__ wscorrect, float* __restrict__ out) {
  const size_t base = (size_t)Bn * Tn + (size_t)Tn * Bn * Sn;
  out[base] = wsloss[0];
  out[base + 1] = (float)wscorrect[0];
}

extern "C" void kernel_launch(void* const* d_in, const int* in_sizes, int n_in,
                              void* d_out, int out_size, void* d_ws, size_t ws_size,
                              hipStream_t stream) {
  const float* state = (const float*)d_in[0];
  const float* enc = (const float*)d_in[1];
  const int* target = (const int*)d_in[2];
  const float* emb = (const float*)d_in[3];
  const float* Wa = (const float*)d_in[4];
  const float* bWa = (const float*)d_in[5];
  const float* Ua = (const float*)d_in[6];
  const float* bUa = (const float*)d_in[7];
  const float* Va = (const float*)d_in[8];
  const float* bVa = (const float*)d_in[9];
  const float* Wih0 = (const float*)d_in[10];
  const float* Whh0 = (const float*)d_in[11];
  const float* bih0 = (const float*)d_in[12];
  const float* bhh0 = (const float*)d_in[13];
  const float* Wih1 = (const float*)d_in[14];
  const float* Whh1 = (const float*)d_in[15];
  const float* bih1 = (const float*)d_in[16];
  const float* bhh1 = (const float*)d_in[17];
  const float* fcW = (const float*)d_in[18];
  const float* fcb = (const float*)d_in[19];
  float* out = (float*)d_out;

  const size_t KPROJ_FLOATS = (size_t)Sn * Bn * Hn;  // 16,777,216 (64 MB)
  if (ws_size >= KPROJ_FLOATS * 4 + 256) {
    // Path A: kproj in workspace, R=4 persistent decoder.
    float* kproj = (float*)d_ws;
    float* wsloss = (float*)d_ws + KPROJ_FLOATS;
    int* wscorrect = (int*)((float*)d_ws + KPROJ_FLOATS + 1);
    ws_init<<<1, 1, 0, stream>>>(wsloss, wscorrect);
    gemm_bias<<<dim3(Hn / 64, (Sn * Bn) / 64), 256, 0, stream>>>(
        enc, Ua, bUa, kproj, Sn * Bn, Hn, Hn);
    decoder_r4<<<Bn / 4, 512, 0, stream>>>(
        state, enc, target, emb, Wa, bWa, Va, bVa, Wih0, Whh0, bih0, bhh0,
        Wih1, Whh1, bih1, bhh1, fcW, fcb, kproj, out, wsloss, wscorrect);
    finisher<<<1, 1, 0, stream>>>(wsloss, wscorrect, out);
  } else {
    // Path B: verified fallback (R=2, kproj in LDS).
    float* wsloss = (float*)d_ws;
    int* wscorrect = (int*)d_ws + 1;
    hipFuncSetAttribute((const void*)decoder_persist,
                        hipFuncAttributeMaxDynamicSharedMemorySize, LDS_BYTES);
    ws_init<<<1, 1, 0, stream>>>(wsloss, wscorrect);
    decoder_persist<<<Bn / 2, 512, LDS_BYTES, stream>>>(
        state, enc, target, emb, Wa, bWa, Ua, bUa, Va, bVa, Wih0, Whh0, bih0, bhh0,
        Wih1, Whh1, bih1, bhh1, fcW, fcb, out, wsloss, wscorrect);
    finisher<<<1, 1, 0, stream>>>(wsloss, wscorrect, out);
  }
}

// Round 7
// 11003.357 us; speedup vs baseline: 5.2306x; 1.6265x over previous
//
#include <hip/hip_runtime.h>
#include <math.h>

#define Hn 512
#define En 256
#define Sn 32
#define Bn 1024
#define Tn 32
#define Vn 256
#define G3 1536
#define EHn 768

// fma4 as a FUNCTION, not a macro: a macro parameter named `w` would get
// substituted into the member access `.w` (R6 compile failure).
__device__ __forceinline__ void fma4(float& acc, const float4 w, const float4 x) {
  acc = fmaf(w.x, x.x, acc);
  acc = fmaf(w.y, x.y, acc);
  acc = fmaf(w.z, x.z, acc);
  acc = fmaf(w.w, x.w, acc);
}

// ============ one-time weight transpose: W[gate][K] -> WT4[k/4][gate] ============
// WT4[k4*G + g] = float4(W[g][4k4 .. 4k4+3]). Writes coalesced.
__global__ __launch_bounds__(256) void transpose_pack(const float* __restrict__ W,
                                                      float4* __restrict__ WT4,
                                                      int G, int K) {
  const int idx = blockIdx.x * blockDim.x + threadIdx.x;
  const int n = G * (K >> 2);
  if (idx >= n) return;
  const int k4 = idx / G, g = idx - k4 * G;
  WT4[idx] = *(const float4*)(W + (size_t)g * K + (k4 << 2));
}

// ============ kproj GEMM: C(M,N) = A(M,K) @ W(N,K)^T + bias ============
__global__ __launch_bounds__(256) void gemm_bias(const float* __restrict__ A,
                                                 const float* __restrict__ Wt,
                                                 const float* __restrict__ bias,
                                                 float* __restrict__ C,
                                                 int M, int N, int K) {
  __shared__ float As[16][68];
  __shared__ float Ws[16][68];
  const int bm = blockIdx.y * 64;
  const int bn = blockIdx.x * 64;
  const int tid = threadIdx.x;
  const int tx = tid & 15;
  const int ty = tid >> 4;
  const int kk = tid & 15;
  const int r0 = tid >> 4;
  float acc[4][4] = {};
  for (int k0 = 0; k0 < K; k0 += 16) {
#pragma unroll
    for (int i = 0; i < 4; ++i) {
      const int m = r0 + (i << 4);
      As[kk][m] = A[(size_t)(bm + m) * K + (k0 + kk)];
      Ws[kk][m] = Wt[(size_t)(bn + m) * K + (k0 + kk)];
    }
    __syncthreads();
#pragma unroll
    for (int k = 0; k < 16; ++k) {
      const float4 a4 = *(const float4*)&As[k][ty * 4];
      const float4 w4 = *(const float4*)&Ws[k][tx * 4];
      const float av[4] = {a4.x, a4.y, a4.z, a4.w};
      const float wv[4] = {w4.x, w4.y, w4.z, w4.w};
#pragma unroll
      for (int i = 0; i < 4; ++i)
#pragma unroll
        for (int j = 0; j < 4; ++j) acc[i][j] = fmaf(av[i], wv[j], acc[i][j]);
    }
    __syncthreads();
  }
#pragma unroll
  for (int i = 0; i < 4; ++i) {
    const size_t m = (size_t)bm + ty * 4 + i;
    float* crow = C + m * N + bn + tx * 4;
#pragma unroll
    for (int j = 0; j < 4; ++j) crow[j] = acc[i][j] + bias[bn + tx * 4 + j];
  }
}

// GRU layer, transposed coalesced weights. Thread j owns gates {j, j+512, j+1024}.
__device__ __forceinline__ void gru_layer4t(
    int j, const float4* __restrict__ WihT, int Kih,
    const float4* __restrict__ WhhT,
    const float* __restrict__ x, int xstride,  // LDS [4][xstride]
    float* __restrict__ h,                     // LDS [4][Hn]
    const float* __restrict__ bih, const float* __restrict__ bhh) {
  float ai0[4] = {}, ai1[4] = {}, ai2[4] = {};
  {
    const float4* w0 = WihT + j;
    const float4* w1 = WihT + j + 512;
    const float4* w2 = WihT + j + 1024;
    for (int k4 = 0; k4 < (Kih >> 2); ++k4) {
      const float4 a = *w0; w0 += G3;
      const float4 b = *w1; w1 += G3;
      const float4 c = *w2; w2 += G3;
#pragma unroll
      for (int r = 0; r < 4; ++r) {
        const float4 xv = ((const float4*)(x + r * xstride))[k4];
        fma4(ai0[r], a, xv);
        fma4(ai1[r], b, xv);
        fma4(ai2[r], c, xv);
      }
    }
  }
  float ah0[4] = {}, ah1[4] = {}, ah2[4] = {};
  {
    const float4* w0 = WhhT + j;
    const float4* w1 = WhhT + j + 512;
    const float4* w2 = WhhT + j + 1024;
    for (int k4 = 0; k4 < (Hn >> 2); ++k4) {
      const float4 a = *w0; w0 += G3;
      const float4 b = *w1; w1 += G3;
      const float4 c = *w2; w2 += G3;
#pragma unroll
      for (int r = 0; r < 4; ++r) {
        const float4 xv = ((const float4*)(h + r * Hn))[k4];
        fma4(ah0[r], a, xv);
        fma4(ah1[r], b, xv);
        fma4(ah2[r], c, xv);
      }
    }
  }
  const float bi0 = bih[j], bi1 = bih[j + 512], bi2 = bih[j + 1024];
  const float bh0 = bhh[j], bh1 = bhh[j + 512], bh2 = bhh[j + 1024];
  float hn[4];
#pragma unroll
  for (int r = 0; r < 4; ++r) {
    const float ir = ai0[r] + bi0, iz = ai1[r] + bi1, in_ = ai2[r] + bi2;
    const float hr = ah0[r] + bh0, hz = ah1[r] + bh1, hnn = ah2[r] + bh2;
    const float rg = 1.f / (1.f + expf(-(ir + hr)));
    const float zg = 1.f / (1.f + expf(-(iz + hz)));
    const float ng = tanhf(in_ + rg * hnn);
    hn[r] = (1.f - zg) * ng + zg * h[r * Hn + j];
  }
  __syncthreads();
#pragma unroll
  for (int r = 0; r < 4; ++r) h[r * Hn + j] = hn[r];
  __syncthreads();
}

// ============ Path A2: R=4 persistent decoder, coalesced transposed weights ======
__global__ __launch_bounds__(512, 1) void decoder_r4t(
    const float* __restrict__ state, const float* __restrict__ enc,
    const int* __restrict__ target, const float* __restrict__ emb,
    const float4* __restrict__ WaT, const float* __restrict__ bWa,
    const float* __restrict__ Va, const float* __restrict__ bVa,
    const float4* __restrict__ W0ihT, const float4* __restrict__ W0hhT,
    const float* __restrict__ bih0, const float* __restrict__ bhh0,
    const float4* __restrict__ W1ihT, const float4* __restrict__ W1hhT,
    const float* __restrict__ bih1, const float* __restrict__ bhh1,
    const float4* __restrict__ fcWT, const float* __restrict__ fcb,
    const float* __restrict__ kproj, float* __restrict__ out,
    float* __restrict__ wsloss, int* __restrict__ wscorrect) {
  __shared__ float h0s[4 * Hn], h1s[4 * Hn], qps[4 * Hn], gins[4 * EHn], vas[Hn];
  __shared__ float red[1024], lg[1024];
  __shared__ int ridx[1024];
  __shared__ float wrs[4 * Sn];
  __shared__ float mxv[4], lzv[4], llv[4];
  __shared__ int amv[4], tgv[4], tokb[4], mfs[4];

  const int tid = threadIdx.x;
  const int b0 = blockIdx.x * 4;

  for (int i = tid; i < 4 * Hn; i += 512) {
    const int r = i >> 9, j = i & 511;
    h0s[i] = state[(size_t)(b0 + r) * Hn + j];
    h1s[i] = state[(size_t)(Bn + b0 + r) * Hn + j];
  }
  vas[tid] = Va[tid];
  if (tid < 4) { tokb[tid] = 1; mfs[tid] = 1; llv[tid] = 0.f; }
  __syncthreads();

  float run_loss = 0.f;  // tid 0 only

  for (int t = 0; t < Tn; ++t) {
    // ---- qp = h1 @ Wa^T + bWa; thread h owns gate h; coalesced WaT reads ----
    {
      const int h = tid;
      const float4* wp = WaT + h;
      float a0 = 0.f, a1 = 0.f, a2 = 0.f, a3 = 0.f;
      for (int k4 = 0; k4 < (Hn >> 2); ++k4) {
        const float4 w = *wp; wp += Hn;
        const float4 x0 = ((const float4*)(h1s))[k4];
        const float4 x1 = ((const float4*)(h1s + Hn))[k4];
        const float4 x2 = ((const float4*)(h1s + 2 * Hn))[k4];
        const float4 x3 = ((const float4*)(h1s + 3 * Hn))[k4];
        fma4(a0, w, x0); fma4(a1, w, x1); fma4(a2, w, x2); fma4(a3, w, x3);
      }
      const float bb = bWa[h];
      qps[h] = a0 + bb; qps[Hn + h] = a1 + bb;
      qps[2 * Hn + h] = a2 + bb; qps[3 * Hn + h] = a3 + bb;
    }
    __syncthreads();
    // ---- e: 4 threads per (r,s) pair; kproj streamed from global ----
    {
      const int p = tid >> 2, q = tid & 3;  // p = r*32+s
      const int r = p >> 5, s = p & 31;
      const float4* kp4 = (const float4*)(kproj + ((size_t)s * Bn + (b0 + r)) * Hn);
      const float4* qp4 = (const float4*)(qps + r * Hn);
      const float4* va4 = (const float4*)vas;
      float partial = 0.f;
      for (int i = 0; i < 32; ++i) {
        const int f = q + (i << 2);
        const float4 k4 = kp4[f], q4 = qp4[f], v4 = va4[f];
        partial += v4.x * tanhf(q4.x + k4.x);
        partial += v4.y * tanhf(q4.y + k4.y);
        partial += v4.z * tanhf(q4.z + k4.z);
        partial += v4.w * tanhf(q4.w + k4.w);
      }
      red[tid] = partial;
    }
    __syncthreads();
    if (tid < 128) {
      float e = red[tid * 4] + red[tid * 4 + 1] + red[tid * 4 + 2] + red[tid * 4 + 3] + bVa[0];
      float m = e;
#pragma unroll
      for (int off = 16; off; off >>= 1) m = fmaxf(m, __shfl_xor(m, off));
      const float ex = expf(e - m);
      float ss = ex;
#pragma unroll
      for (int off = 16; off; off >>= 1) ss += __shfl_xor(ss, off);
      const float w = ex / ss;
      const int r = tid >> 5, s = tid & 31;
      wrs[tid] = w;
      out[(size_t)(Bn * Tn) + (size_t)t * (Bn * Sn) + (size_t)(b0 + r) * Sn + s] = w;
    }
    __syncthreads();
    // ---- context (coalesced enc reads) + relu(emb[tok]) -> gin ----
    {
      const int h = tid;
      float c0 = 0.f, c1 = 0.f, c2 = 0.f, c3 = 0.f;
      for (int s = 0; s < Sn; ++s) {
        const size_t base = ((size_t)s * Bn + b0) * Hn + h;
        c0 = fmaf(wrs[s], enc[base], c0);
        c1 = fmaf(wrs[32 + s], enc[base + Hn], c1);
        c2 = fmaf(wrs[64 + s], enc[base + 2 * Hn], c2);
        c3 = fmaf(wrs[96 + s], enc[base + 3 * Hn], c3);
      }
      gins[En + h] = c0; gins[EHn + En + h] = c1;
      gins[2 * EHn + En + h] = c2; gins[3 * EHn + En + h] = c3;
    }
    for (int i = tid; i < 4 * En; i += 512) {
      const int r = i >> 8, j = i & 255;
      gins[r * EHn + j] = fmaxf(emb[(size_t)tokb[r] * En + j], 0.f);
    }
    __syncthreads();
    // ---- GRU layers (coalesced transposed weights) ----
    gru_layer4t(tid, W0ihT, EHn, W0hhT, gins, EHn, h0s, bih0, bhh0);
    gru_layer4t(tid, W1ihT, Hn, W1hhT, h0s, Hn, h1s, bih1, bhh1);
    // ---- fc: thread = (v, row-pair); coalesced fcWT reads ----
    {
      const int v = tid & 255;
      const int rA = tid >> 8, rB = rA + 2;
      const float4* wp = fcWT + v;
      float aA = 0.f, aB = 0.f;
      for (int k4 = 0; k4 < (Hn >> 2); ++k4) {
        const float4 w = *wp; wp += Vn;
        const float4 a = ((const float4*)(h1s + rA * Hn))[k4];
        const float4 b = ((const float4*)(h1s + rB * Hn))[k4];
        fma4(aA, w, a); fma4(aB, w, b);
      }
      const float fb = fcb[v];
      const float lA = aA + fb, lB = aB + fb;
      lg[rA * 256 + v] = lA; red[rA * 256 + v] = lA; ridx[rA * 256 + v] = v;
      lg[rB * 256 + v] = lB; red[rB * 256 + v] = lB; ridx[rB * 256 + v] = v;
    }
    __syncthreads();
    // argmax (first-max tie-break) per 256-segment
    for (int off = 128; off; off >>= 1) {
#pragma unroll
      for (int half = 0; half < 2; ++half) {
        const int u = tid + half * 512;
        if ((u & 255) < off) {
          const int u2 = u + off;
          const float o = red[u2]; const int oi = ridx[u2];
          if (o > red[u] || (o == red[u] && oi < ridx[u])) { red[u] = o; ridx[u] = oi; }
        }
      }
      __syncthreads();
    }
    if (tid < 4) {
      mxv[tid] = red[tid * 256];
      amv[tid] = ridx[tid * 256];
      tgv[tid] = target[(size_t)(b0 + tid) * Tn + t];
    }
    __syncthreads();
#pragma unroll
    for (int half = 0; half < 2; ++half) {
      const int u = tid + half * 512;
      red[u] = expf(lg[u] - mxv[u >> 8]);
    }
    __syncthreads();
    for (int off = 128; off; off >>= 1) {
#pragma unroll
      for (int half = 0; half < 2; ++half) {
        const int u = tid + half * 512;
        if ((u & 255) < off) red[u] += red[u + off];
      }
      __syncthreads();
    }
    if (tid < 4) {
      const int r = tid;
      lzv[r] = logf(red[r * 256]);
      tokb[r] = amv[r];
      if (amv[r] != tgv[r]) mfs[r] = 0;
      out[(size_t)(b0 + r) * Tn + t] = (float)amv[r];
    }
    __syncthreads();
#pragma unroll
    for (int half = 0; half < 2; ++half) {
      const int u = tid + half * 512;
      const int r = u >> 8, v = u & 255;
      if (v == tgv[r]) llv[r] = -(lg[u] - mxv[r] - lzv[r]) * (1.f / 1024.f);
    }
    __syncthreads();
    if (tid == 0) run_loss += llv[0] + llv[1] + llv[2] + llv[3];
    __syncthreads();
  }

  if (tid == 0) {
    atomicAdd(wsloss, run_loss);
    atomicAdd(wscorrect, mfs[0] + mfs[1] + mfs[2] + mfs[3]);
  }
}

// ============ Path A fallback: Round-5 decoder (uncoalesced weights) ============
__device__ __forceinline__ void gru_layer4(int j, const float* __restrict__ x,
                                           int xstride, int K,
                                           float* __restrict__ h,
                                           const float* __restrict__ Wih,
                                           const float* __restrict__ Whh,
                                           const float* __restrict__ bih,
                                           const float* __restrict__ bhh) {
  float ai0[4] = {}, ai1[4] = {}, ai2[4] = {};
  {
    const float4* w0 = (const float4*)(Wih + (size_t)j * K);
    const float4* w1 = (const float4*)(Wih + (size_t)(j + 512) * K);
    const float4* w2 = (const float4*)(Wih + (size_t)(j + 1024) * K);
    for (int i = 0; i < K / 4; ++i) {
      const float4 a = w0[i], b = w1[i], c = w2[i];
#pragma unroll
      for (int r = 0; r < 4; ++r) {
        const float4 xv = ((const float4*)(x + r * xstride))[i];
        fma4(ai0[r], a, xv); fma4(ai1[r], b, xv); fma4(ai2[r], c, xv);
      }
    }
  }
  float ah0[4] = {}, ah1[4] = {}, ah2[4] = {};
  {
    const float4* w0 = (const float4*)(Whh + (size_t)j * Hn);
    const float4* w1 = (const float4*)(Whh + (size_t)(j + 512) * Hn);
    const float4* w2 = (const float4*)(Whh + (size_t)(j + 1024) * Hn);
    for (int i = 0; i < Hn / 4; ++i) {
      const float4 a = w0[i], b = w1[i], c = w2[i];
#pragma unroll
      for (int r = 0; r < 4; ++r) {
        const float4 xv = ((const float4*)(h + r * Hn))[i];
        fma4(ah0[r], a, xv); fma4(ah1[r], b, xv); fma4(ah2[r], c, xv);
      }
    }
  }
  const float bi0 = bih[j], bi1 = bih[j + 512], bi2 = bih[j + 1024];
  const float bh0 = bhh[j], bh1 = bhh[j + 512], bh2 = bhh[j + 1024];
  float hn[4];
#pragma unroll
  for (int r = 0; r < 4; ++r) {
    const float ir = ai0[r] + bi0, iz = ai1[r] + bi1, in_ = ai2[r] + bi2;
    const float hr = ah0[r] + bh0, hz = ah1[r] + bh1, hnn = ah2[r] + bh2;
    const float rg = 1.f / (1.f + expf(-(ir + hr)));
    const float zg = 1.f / (1.f + expf(-(iz + hz)));
    const float ng = tanhf(in_ + rg * hnn);
    hn[r] = (1.f - zg) * ng + zg * h[r * Hn + j];
  }
  __syncthreads();
#pragma unroll
  for (int r = 0; r < 4; ++r) h[r * Hn + j] = hn[r];
  __syncthreads();
}

__global__ __launch_bounds__(512, 1) void decoder_r4(
    const float* __restrict__ state, const float* __restrict__ enc,
    const int* __restrict__ target, const float* __restrict__ emb,
    const float* __restrict__ Wa, const float* __restrict__ bWa,
    const float* __restrict__ Va, const float* __restrict__ bVa,
    const float* __restrict__ Wih0, const float* __restrict__ Whh0,
    const float* __restrict__ bih0, const float* __restrict__ bhh0,
    const float* __restrict__ Wih1, const float* __restrict__ Whh1,
    const float* __restrict__ bih1, const float* __restrict__ bhh1,
    const float* __restrict__ fcW, const float* __restrict__ fcb,
    const float* __restrict__ kproj, float* __restrict__ out,
    float* __restrict__ wsloss, int* __restrict__ wscorrect) {
  __shared__ float h0s[4 * Hn], h1s[4 * Hn], qps[4 * Hn], gins[4 * EHn], vas[Hn];
  __shared__ float red[1024], lg[1024];
  __shared__ int ridx[1024];
  __shared__ float wrs[4 * Sn];
  __shared__ float mxv[4], lzv[4], llv[4];
  __shared__ int amv[4], tgv[4], tokb[4], mfs[4];

  const int tid = threadIdx.x;
  const int b0 = blockIdx.x * 4;

  for (int i = tid; i < 4 * Hn; i += 512) {
    const int r = i >> 9, j = i & 511;
    h0s[i] = state[(size_t)(b0 + r) * Hn + j];
    h1s[i] = state[(size_t)(Bn + b0 + r) * Hn + j];
  }
  vas[tid] = Va[tid];
  if (tid < 4) { tokb[tid] = 1; mfs[tid] = 1; llv[tid] = 0.f; }
  __syncthreads();

  float run_loss = 0.f;

  for (int t = 0; t < Tn; ++t) {
    {
      const int h = tid;
      const float4* w4 = (const float4*)(Wa + (size_t)h * Hn);
      float a0 = 0.f, a1 = 0.f, a2 = 0.f, a3 = 0.f;
      for (int i = 0; i < Hn / 4; ++i) {
        const float4 w = w4[i];
        const float4 x0 = ((const float4*)(h1s))[i];
        const float4 x1 = ((const float4*)(h1s + Hn))[i];
        const float4 x2 = ((const float4*)(h1s + 2 * Hn))[i];
        const float4 x3 = ((const float4*)(h1s + 3 * Hn))[i];
        fma4(a0, w, x0); fma4(a1, w, x1); fma4(a2, w, x2); fma4(a3, w, x3);
      }
      const float bb = bWa[h];
      qps[h] = a0 + bb; qps[Hn + h] = a1 + bb;
      qps[2 * Hn + h] = a2 + bb; qps[3 * Hn + h] = a3 + bb;
    }
    __syncthreads();
    {
      const int p = tid >> 2, q = tid & 3;
      const int r = p >> 5, s = p & 31;
      const float4* kp4 = (const float4*)(kproj + ((size_t)s * Bn + (b0 + r)) * Hn);
      const float4* qp4 = (const float4*)(qps + r * Hn);
      const float4* va4 = (const float4*)vas;
      float partial = 0.f;
      for (int i = 0; i < 32; ++i) {
        const int f = q + (i << 2);
        const float4 k4 = kp4[f], q4 = qp4[f], v4 = va4[f];
        partial += v4.x * tanhf(q4.x + k4.x);
        partial += v4.y * tanhf(q4.y + k4.y);
        partial += v4.z * tanhf(q4.z + k4.z);
        partial += v4.w * tanhf(q4.w + k4.w);
      }
      red[tid] = partial;
    }
    __syncthreads();
    if (tid < 128) {
      float e = red[tid * 4] + red[tid * 4 + 1] + red[tid * 4 + 2] + red[tid * 4 + 3] + bVa[0];
      float m = e;
#pragma unroll
      for (int off = 16; off; off >>= 1) m = fmaxf(m, __shfl_xor(m, off));
      const float ex = expf(e - m);
      float ss = ex;
#pragma unroll
      for (int off = 16; off; off >>= 1) ss += __shfl_xor(ss, off);
      const float w = ex / ss;
      const int r = tid >> 5, s = tid & 31;
      wrs[tid] = w;
      out[(size_t)(Bn * Tn) + (size_t)t * (Bn * Sn) + (size_t)(b0 + r) * Sn + s] = w;
    }
    __syncthreads();
    {
      const int h = tid;
      float c0 = 0.f, c1 = 0.f, c2 = 0.f, c3 = 0.f;
      for (int s = 0; s < Sn; ++s) {
        const size_t base = ((size_t)s * Bn + b0) * Hn + h;
        c0 = fmaf(wrs[s], enc[base], c0);
        c1 = fmaf(wrs[32 + s], enc[base + Hn], c1);
        c2 = fmaf(wrs[64 + s], enc[base + 2 * Hn], c2);
        c3 = fmaf(wrs[96 + s], enc[base + 3 * Hn], c3);
      }
      gins[En + h] = c0; gins[EHn + En + h] = c1;
      gins[2 * EHn + En + h] = c2; gins[3 * EHn + En + h] = c3;
    }
    for (int i = tid; i < 4 * En; i += 512) {
      const int r = i >> 8, j = i & 255;
      gins[r * EHn + j] = fmaxf(emb[(size_t)tokb[r] * En + j], 0.f);
    }
    __syncthreads();
    gru_layer4(tid, gins, EHn, EHn, h0s, Wih0, Whh0, bih0, bhh0);
    gru_layer4(tid, h0s, Hn, Hn, h1s, Wih1, Whh1, bih1, bhh1);
    {
      const int v = tid & 255;
      const int rA = tid >> 8, rB = rA + 2;
      const float4* w4 = (const float4*)(fcW + (size_t)v * Hn);
      const float4* xA = (const float4*)(h1s + rA * Hn);
      const float4* xB = (const float4*)(h1s + rB * Hn);
      float aA = 0.f, aB = 0.f;
      for (int i = 0; i < Hn / 4; ++i) {
        const float4 w = w4[i];
        const float4 a = xA[i], b = xB[i];
        fma4(aA, w, a); fma4(aB, w, b);
      }
      const float fb = fcb[v];
      const float lA = aA + fb, lB = aB + fb;
      lg[rA * 256 + v] = lA; red[rA * 256 + v] = lA; ridx[rA * 256 + v] = v;
      lg[rB * 256 + v] = lB; red[rB * 256 + v] = lB; ridx[rB * 256 + v] = v;
    }
    __syncthreads();
    for (int off = 128; off; off >>= 1) {
#pragma unroll
      for (int half = 0; half < 2; ++half) {
        const int u = tid + half * 512;
        if ((u & 255) < off) {
          const int u2 = u + off;
          const float o = red[u2]; const int oi = ridx[u2];
          if (o > red[u] || (o == red[u] && oi < ridx[u])) { red[u] = o; ridx[u] = oi; }
        }
      }
      __syncthreads();
    }
    if (tid < 4) {
      mxv[tid] = red[tid * 256];
      amv[tid] = ridx[tid * 256];
      tgv[tid] = target[(size_t)(b0 + tid) * Tn + t];
    }
    __syncthreads();
#pragma unroll
    for (int half = 0; half < 2; ++half) {
      const int u = tid + half * 512;
      red[u] = expf(lg[u] - mxv[u >> 8]);
    }
    __syncthreads();
    for (int off = 128; off; off >>= 1) {
#pragma unroll
      for (int half = 0; half < 2; ++half) {
        const int u = tid + half * 512;
        if ((u & 255) < off) red[u] += red[u + off];
      }
      __syncthreads();
    }
    if (tid < 4) {
      const int r = tid;
      lzv[r] = logf(red[r * 256]);
      tokb[r] = amv[r];
      if (amv[r] != tgv[r]) mfs[r] = 0;
      out[(size_t)(b0 + r) * Tn + t] = (float)amv[r];
    }
    __syncthreads();
#pragma unroll
    for (int half = 0; half < 2; ++half) {
      const int u = tid + half * 512;
      const int r = u >> 8, v = u & 255;
      if (v == tgv[r]) llv[r] = -(lg[u] - mxv[r] - lzv[r]) * (1.f / 1024.f);
    }
    __syncthreads();
    if (tid == 0) run_loss += llv[0] + llv[1] + llv[2] + llv[3];
    __syncthreads();
  }

  if (tid == 0) {
    atomicAdd(wsloss, run_loss);
    atomicAdd(wscorrect, mfs[0] + mfs[1] + mfs[2] + mfs[3]);
  }
}

// ============ common epilogue ============
__global__ void ws_init(float* wsloss, int* wscorrect) {
  wsloss[0] = 0.f;
  wscorrect[0] = 0;
}

__global__ void finisher(const float* __restrict__ wsloss,
                         const int* __restrict__ wscorrect, float* __restrict__ out) {
  const size_t base = (size_t)Bn * Tn + (size_t)Tn * Bn * Sn;
  out[base] = wsloss[0];
  out[base + 1] = (float)wscorrect[0];
}

extern "C" void kernel_launch(void* const* d_in, const int* in_sizes, int n_in,
                              void* d_out, int out_size, void* d_ws, size_t ws_size,
                              hipStream_t stream) {
  const float* state = (const float*)d_in[0];
  const float* enc = (const float*)d_in[1];
  const int* target = (const int*)d_in[2];
  const float* emb = (const float*)d_in[3];
  const float* Wa = (const float*)d_in[4];
  const float* bWa = (const float*)d_in[5];
  const float* Ua = (const float*)d_in[6];
  const float* bUa = (const float*)d_in[7];
  const float* Va = (const float*)d_in[8];
  const float* bVa = (const float*)d_in[9];
  const float* Wih0 = (const float*)d_in[10];
  const float* Whh0 = (const float*)d_in[11];
  const float* bih0 = (const float*)d_in[12];
  const float* bhh0 = (const float*)d_in[13];
  const float* Wih1 = (const float*)d_in[14];
  const float* Whh1 = (const float*)d_in[15];
  const float* bih1 = (const float*)d_in[16];
  const float* bhh1 = (const float*)d_in[17];
  const float* fcW = (const float*)d_in[18];
  const float* fcb = (const float*)d_in[19];
  float* out = (float*)d_out;

  const size_t KPROJ_FLOATS = (size_t)Sn * Bn * Hn;  // 64 MB

  // transposed-weight float4 counts
  const size_t N0IH = (size_t)G3 * (EHn / 4);  // 294912
  const size_t NHH = (size_t)G3 * (Hn / 4);    // 196608
  const size_t NWA = (size_t)Hn * (Hn / 4);    // 65536
  const size_t NFC = (size_t)Vn * (Hn / 4);    // 32768
  const size_t WT_TOTAL = N0IH + 3 * NHH + NWA + NFC;  // 983040 f4 = 15 MB
  const size_t NEED_A2 = WT_TOTAL * 16 + KPROJ_FLOATS * 4 + 256;

  if (ws_size >= NEED_A2) {
    // Path A2: transposed weights + kproj in workspace, coalesced decoder.
    float4* W0ihT = (float4*)d_ws;
    float4* W0hhT = W0ihT + N0IH;
    float4* W1ihT = W0hhT + NHH;
    float4* W1hhT = W1ihT + NHH;
    float4* WaT = W1hhT + NHH;
    float4* fcWT = WaT + NWA;
    float* kproj = (float*)(fcWT + NFC);
    float* wsloss = kproj + KPROJ_FLOATS;
    int* wscorrect = (int*)(wsloss + 1);

    ws_init<<<1, 1, 0, stream>>>(wsloss, wscorrect);
    transpose_pack<<<(int)((N0IH + 255) / 256), 256, 0, stream>>>(Wih0, W0ihT, G3, EHn);
    transpose_pack<<<(int)((NHH + 255) / 256), 256, 0, stream>>>(Whh0, W0hhT, G3, Hn);
    transpose_pack<<<(int)((NHH + 255) / 256), 256, 0, stream>>>(Wih1, W1ihT, G3, Hn);
    transpose_pack<<<(int)((NHH + 255) / 256), 256, 0, stream>>>(Whh1, W1hhT, G3, Hn);
    transpose_pack<<<(int)((NWA + 255) / 256), 256, 0, stream>>>(Wa, WaT, Hn, Hn);
    transpose_pack<<<(int)((NFC + 255) / 256), 256, 0, stream>>>(fcW, fcWT, Vn, Hn);
    gemm_bias<<<dim3(Hn / 64, (Sn * Bn) / 64), 256, 0, stream>>>(
        enc, Ua, bUa, kproj, Sn * Bn, Hn, Hn);
    decoder_r4t<<<Bn / 4, 512, 0, stream>>>(
        state, enc, target, emb, WaT, bWa, Va, bVa, W0ihT, W0hhT, bih0, bhh0,
        W1ihT, W1hhT, bih1, bhh1, fcWT, fcb, kproj, out, wsloss, wscorrect);
    finisher<<<1, 1, 0, stream>>>(wsloss, wscorrect, out);
  } else {
    // Path A (Round-5 verified): kproj in workspace, uncoalesced weights.
    float* kproj = (float*)d_ws;
    float* wsloss = (float*)d_ws + KPROJ_FLOATS;
    int* wscorrect = (int*)((float*)d_ws + KPROJ_FLOATS + 1);
    ws_init<<<1, 1, 0, stream>>>(wsloss, wscorrect);
    gemm_bias<<<dim3(Hn / 64, (Sn * Bn) / 64), 256, 0, stream>>>(
        enc, Ua, bUa, kproj, Sn * Bn, Hn, Hn);
    decoder_r4<<<Bn / 4, 512, 0, stream>>>(
        state, enc, target, emb, Wa, bWa, Va, bVa, Wih0, Whh0, bih0, bhh0,
        Wih1, Whh1, bih1, bhh1, fcW, fcb, kproj, out, wsloss, wscorrect);
    finisher<<<1, 1, 0, stream>>>(wsloss, wscorrect, out);
  }
}

// Round 8
// 10858.581 us; speedup vs baseline: 5.3003x; 1.0133x over previous
//
#include <hip/hip_runtime.h>
#include <math.h>

#define Hn 512
#define En 256
#define Sn 32
#define Bn 1024
#define Tn 32
#define Vn 256
#define G3 1536
#define EHn 768

// fma4 as a FUNCTION, not a macro (R6 lesson: macro param `w` collides with `.w`).
__device__ __forceinline__ void fma4(float& acc, const float4 w, const float4 x) {
  acc = fmaf(w.x, x.x, acc);
  acc = fmaf(w.y, x.y, acc);
  acc = fmaf(w.z, x.z, acc);
  acc = fmaf(w.w, x.w, acc);
}

// ============ one-time weight transpose: W[gate][K] -> WT4[k4*G + g] ============
__global__ __launch_bounds__(256) void transpose_pack(const float* __restrict__ W,
                                                      float4* __restrict__ WT4,
                                                      int G, int K) {
  const int idx = blockIdx.x * blockDim.x + threadIdx.x;
  const int n = G * (K >> 2);
  if (idx >= n) return;
  const int k4 = idx / G, g = idx - k4 * G;
  WT4[idx] = *(const float4*)(W + (size_t)g * K + (k4 << 2));
}

// ============ kproj GEMM: C(M,N) = A(M,K) @ W(N,K)^T + bias ============
__global__ __launch_bounds__(256) void gemm_bias(const float* __restrict__ A,
                                                 const float* __restrict__ Wt,
                                                 const float* __restrict__ bias,
                                                 float* __restrict__ C,
                                                 int M, int N, int K) {
  __shared__ float As[16][68];
  __shared__ float Ws[16][68];
  const int bm = blockIdx.y * 64;
  const int bn = blockIdx.x * 64;
  const int tid = threadIdx.x;
  const int tx = tid & 15;
  const int ty = tid >> 4;
  const int kk = tid & 15;
  const int r0 = tid >> 4;
  float acc[4][4] = {};
  for (int k0 = 0; k0 < K; k0 += 16) {
#pragma unroll
    for (int i = 0; i < 4; ++i) {
      const int m = r0 + (i << 4);
      As[kk][m] = A[(size_t)(bm + m) * K + (k0 + kk)];
      Ws[kk][m] = Wt[(size_t)(bn + m) * K + (k0 + kk)];
    }
    __syncthreads();
#pragma unroll
    for (int k = 0; k < 16; ++k) {
      const float4 a4 = *(const float4*)&As[k][ty * 4];
      const float4 w4 = *(const float4*)&Ws[k][tx * 4];
      const float av[4] = {a4.x, a4.y, a4.z, a4.w};
      const float wv[4] = {w4.x, w4.y, w4.z, w4.w};
#pragma unroll
      for (int i = 0; i < 4; ++i)
#pragma unroll
        for (int j = 0; j < 4; ++j) acc[i][j] = fmaf(av[i], wv[j], acc[i][j]);
    }
    __syncthreads();
  }
#pragma unroll
  for (int i = 0; i < 4; ++i) {
    const size_t m = (size_t)bm + ty * 4 + i;
    float* crow = C + m * N + bn + tx * 4;
#pragma unroll
    for (int j = 0; j < 4; ++j) crow[j] = acc[i][j] + bias[bn + tx * 4 + j];
  }
}

// ==================== dynamic-LDS layout for the 1024-thread decoder ============
#define O_H0   0        // [4][512]
#define O_H1   2048
#define O_QP   4096
#define O_GIN  6144     // [4][768]
#define O_VA   9216     // [512]
#define O_WR   9728     // [4][32]
#define O_MX   9856     // float[4]
#define O_LZ   9860
#define O_LL   9864
#define O_AM   9868     // int[4]
#define O_TG   9872
#define O_TOK  9876
#define O_MF   9880
#define O_PRT  9888     // [16][1024] partials (SoA, conflict-free); aliases red/lg/ridx
#define LDS_FLOATS2 (O_PRT + 16 * 1024)   // 26272 floats = 105088 B
#define LDS_BYTES2 (LDS_FLOATS2 * 4)

// GRU layer with K split across thread pairs (tid, tid+512).
// r/z gate partials merge ih+hh; n gates kept separate (r-scaling).
__device__ __forceinline__ void gru_block(
    int tid, const float4* __restrict__ WihT, int Kih,
    const float4* __restrict__ WhhT,
    const float* __restrict__ x, int xstride,  // LDS [4][xstride]
    float* __restrict__ h,                     // LDS [4][Hn]
    const float* __restrict__ bih, const float* __restrict__ bhh,
    float* __restrict__ prt) {
  const int jj = tid & 511;
  const int half = tid >> 9;
  float ar[4] = {}, az[4] = {}, ain[4] = {}, ahn[4] = {};
  {
    const int kc = (Kih >> 2) >> 1;
    const int k0 = half * kc;
    const float4* w0 = WihT + jj + (size_t)k0 * G3;
    const float4* w1 = WihT + jj + 512 + (size_t)k0 * G3;
    const float4* w2 = WihT + jj + 1024 + (size_t)k0 * G3;
    for (int k4 = 0; k4 < kc; ++k4) {
      const float4 a = *w0; w0 += G3;
      const float4 b = *w1; w1 += G3;
      const float4 c = *w2; w2 += G3;
#pragma unroll
      for (int r = 0; r < 4; ++r) {
        const float4 xv = ((const float4*)(x + r * xstride))[k0 + k4];
        fma4(ar[r], a, xv);
        fma4(az[r], b, xv);
        fma4(ain[r], c, xv);
      }
    }
  }
  {
    const int kc = (Hn >> 2) >> 1;
    const int k0 = half * kc;
    const float4* w0 = WhhT + jj + (size_t)k0 * G3;
    const float4* w1 = WhhT + jj + 512 + (size_t)k0 * G3;
    const float4* w2 = WhhT + jj + 1024 + (size_t)k0 * G3;
    for (int k4 = 0; k4 < kc; ++k4) {
      const float4 a = *w0; w0 += G3;
      const float4 b = *w1; w1 += G3;
      const float4 c = *w2; w2 += G3;
#pragma unroll
      for (int r = 0; r < 4; ++r) {
        const float4 xv = ((const float4*)(h + r * Hn))[k0 + k4];
        fma4(ar[r], a, xv);
        fma4(az[r], b, xv);
        fma4(ahn[r], c, xv);
      }
    }
  }
#pragma unroll
  for (int r = 0; r < 4; ++r) {
    prt[r * 1024 + tid] = ar[r];
    prt[(4 + r) * 1024 + tid] = az[r];
    prt[(8 + r) * 1024 + tid] = ain[r];
    prt[(12 + r) * 1024 + tid] = ahn[r];
  }
  __syncthreads();
  float hn[4];
  if (tid < 512) {
    const int j = tid;
    const float bir = bih[j], biz = bih[j + 512], bin = bih[j + 1024];
    const float bhr = bhh[j], bhz = bhh[j + 512], bhn = bhh[j + 1024];
#pragma unroll
    for (int r = 0; r < 4; ++r) {
      const float srr = prt[r * 1024 + j] + prt[r * 1024 + j + 512] + bir + bhr;
      const float szz = prt[(4 + r) * 1024 + j] + prt[(4 + r) * 1024 + j + 512] + biz + bhz;
      const float sin_ = prt[(8 + r) * 1024 + j] + prt[(8 + r) * 1024 + j + 512] + bin;
      const float shn = prt[(12 + r) * 1024 + j] + prt[(12 + r) * 1024 + j + 512] + bhn;
      const float rg = 1.f / (1.f + expf(-srr));
      const float zg = 1.f / (1.f + expf(-szz));
      const float ng = tanhf(sin_ + rg * shn);
      hn[r] = (1.f - zg) * ng + zg * h[r * Hn + j];
    }
  }
  __syncthreads();
  if (tid < 512) {
#pragma unroll
    for (int r = 0; r < 4; ++r) h[r * Hn + tid] = hn[r];
  }
  __syncthreads();
}

// ============ Path A2: R=4, 1024-thread persistent decoder (K-split) ============
__global__ __launch_bounds__(1024, 4) void decoder_r4x(
    const float* __restrict__ state, const float* __restrict__ enc,
    const int* __restrict__ target, const float* __restrict__ emb,
    const float4* __restrict__ WaT, const float* __restrict__ bWa,
    const float* __restrict__ Va, const float* __restrict__ bVa,
    const float4* __restrict__ W0ihT, const float4* __restrict__ W0hhT,
    const float* __restrict__ bih0, const float* __restrict__ bhh0,
    const float4* __restrict__ W1ihT, const float4* __restrict__ W1hhT,
    const float* __restrict__ bih1, const float* __restrict__ bhh1,
    const float4* __restrict__ fcWT, const float* __restrict__ fcb,
    const float* __restrict__ kproj, float* __restrict__ out,
    float* __restrict__ wsloss, int* __restrict__ wscorrect) {
  extern __shared__ float L[];
  float* h0s = L + O_H0;
  float* h1s = L + O_H1;
  float* qps = L + O_QP;
  float* gins = L + O_GIN;
  float* vas = L + O_VA;
  float* wrs = L + O_WR;
  float* mxv = L + O_MX;
  float* lzv = L + O_LZ;
  float* llv = L + O_LL;
  int* amv = (int*)(L + O_AM);
  int* tgv = (int*)(L + O_TG);
  int* tokb = (int*)(L + O_TOK);
  int* mfs = (int*)(L + O_MF);
  float* prt = L + O_PRT;
  float* red = prt;            // 1024 (fc phase only)
  float* lg = prt + 1024;      // 1024
  int* ridx = (int*)(prt + 2048);

  const int tid = threadIdx.x;
  const int b0 = blockIdx.x * 4;

  for (int i = tid; i < 4 * Hn; i += 1024) {
    const int r = i >> 9, j = i & 511;
    h0s[i] = state[(size_t)(b0 + r) * Hn + j];
    h1s[i] = state[(size_t)(Bn + b0 + r) * Hn + j];
  }
  if (tid < 512) vas[tid] = Va[tid];
  if (tid < 4) { tokb[tid] = 1; mfs[tid] = 1; llv[tid] = 0.f; }
  __syncthreads();

  float run_loss = 0.f;  // tid 0 only

  for (int t = 0; t < Tn; ++t) {
    // ---- qp = h1 @ Wa^T + bWa, K split across thread pairs ----
    {
      const int hh = tid & 511, half = tid >> 9;
      const int kc = (Hn >> 2) >> 1;
      const int k0 = half * kc;
      const float4* wp = WaT + hh + (size_t)k0 * Hn;
      float a0 = 0.f, a1 = 0.f, a2 = 0.f, a3 = 0.f;
      for (int k4 = 0; k4 < kc; ++k4) {
        const float4 w = *wp; wp += Hn;
        fma4(a0, w, ((const float4*)(h0s + 0))[0]);  // placeholder avoided below
        a0 -= 0.f;  // (no-op guard removed)
        break;
      }
      // real loop (written plainly to avoid accidental misuse above)
      a0 = a1 = a2 = a3 = 0.f;
      wp = WaT + hh + (size_t)k0 * Hn;
      for (int k4 = 0; k4 < kc; ++k4) {
        const float4 w = *wp; wp += Hn;
        const float4 x0 = ((const float4*)(h1s))[k0 + k4];
        const float4 x1 = ((const float4*)(h1s + Hn))[k0 + k4];
        const float4 x2 = ((const float4*)(h1s + 2 * Hn))[k0 + k4];
        const float4 x3 = ((const float4*)(h1s + 3 * Hn))[k0 + k4];
        fma4(a0, w, x0); fma4(a1, w, x1); fma4(a2, w, x2); fma4(a3, w, x3);
      }
      prt[tid] = a0;
      prt[1024 + tid] = a1;
      prt[2048 + tid] = a2;
      prt[3072 + tid] = a3;
    }
    __syncthreads();
    if (tid < 512) {
      const float bb = bWa[tid];
      qps[tid] = prt[tid] + prt[tid + 512] + bb;
      qps[Hn + tid] = prt[1024 + tid] + prt[1024 + tid + 512] + bb;
      qps[2 * Hn + tid] = prt[2048 + tid] + prt[2048 + tid + 512] + bb;
      qps[3 * Hn + tid] = prt[3072 + tid] + prt[3072 + tid + 512] + bb;
    }
    __syncthreads();
    // ---- e: 8 threads per (r,s) pair; kproj streamed from global ----
    {
      const int p = tid >> 3, q = tid & 7;  // p = r*32+s
      const int r = p >> 5, s = p & 31;
      const float4* kp4 = (const float4*)(kproj + ((size_t)s * Bn + (b0 + r)) * Hn);
      const float4* qp4 = (const float4*)(qps + r * Hn);
      const float4* va4 = (const float4*)vas;
      float partial = 0.f;
      for (int i = 0; i < 16; ++i) {
        const int f = q + (i << 3);
        const float4 k4 = kp4[f], q4 = qp4[f], v4 = va4[f];
        partial += v4.x * tanhf(q4.x + k4.x);
        partial += v4.y * tanhf(q4.y + k4.y);
        partial += v4.z * tanhf(q4.z + k4.z);
        partial += v4.w * tanhf(q4.w + k4.w);
      }
      prt[tid] = partial;
    }
    __syncthreads();
    if (tid < 128) {
      float e = prt[tid * 8] + prt[tid * 8 + 1] + prt[tid * 8 + 2] + prt[tid * 8 + 3] +
                prt[tid * 8 + 4] + prt[tid * 8 + 5] + prt[tid * 8 + 6] + prt[tid * 8 + 7] +
                bVa[0];
      float m = e;
#pragma unroll
      for (int off = 16; off; off >>= 1) m = fmaxf(m, __shfl_xor(m, off));
      const float ex = expf(e - m);
      float ss = ex;
#pragma unroll
      for (int off = 16; off; off >>= 1) ss += __shfl_xor(ss, off);
      const float w = ex / ss;
      const int r = tid >> 5, s = tid & 31;
      wrs[tid] = w;
      out[(size_t)(Bn * Tn) + (size_t)t * (Bn * Sn) + (size_t)(b0 + r) * Sn + s] = w;
    }
    __syncthreads();
    // ---- context (2 rows per thread) + relu(emb[tok]) -> gin ----
    {
      const int h = tid & 511, rp = tid >> 9;  // rows 2rp, 2rp+1
      float c0 = 0.f, c1 = 0.f;
      const float* w0 = wrs + (2 * rp) * 32;
      const float* w1 = wrs + (2 * rp + 1) * 32;
      for (int s = 0; s < Sn; ++s) {
        const size_t base = ((size_t)s * Bn + b0 + 2 * rp) * Hn + h;
        c0 = fmaf(w0[s], enc[base], c0);
        c1 = fmaf(w1[s], enc[base + Hn], c1);
      }
      gins[(2 * rp) * EHn + En + h] = c0;
      gins[(2 * rp + 1) * EHn + En + h] = c1;
    }
    {
      const int r = tid >> 8, j = tid & 255;
      gins[r * EHn + j] = fmaxf(emb[(size_t)tokb[r] * En + j], 0.f);
    }
    __syncthreads();
    // ---- GRU layers (K-split) ----
    gru_block(tid, W0ihT, EHn, W0hhT, gins, EHn, h0s, bih0, bhh0, prt);
    gru_block(tid, W1ihT, Hn, W1hhT, h0s, Hn, h1s, bih1, bhh1, prt);
    // ---- fc: one (v, row) per thread; coalesced fcWT reads ----
    {
      const int v = tid & 255, r = tid >> 8;
      const float4* wp = fcWT + v;
      const float4* xr = (const float4*)(h1s + r * Hn);
      float acc = 0.f;
      for (int k4 = 0; k4 < (Hn >> 2); ++k4) {
        const float4 w = *wp; wp += Vn;
        fma4(acc, w, xr[k4]);
      }
      const float l = acc + fcb[v];
      lg[tid] = l;
      red[tid] = l;
      ridx[tid] = v;
    }
    __syncthreads();
    // argmax (first-max tie-break) per 256-segment
    for (int off = 128; off; off >>= 1) {
      if ((tid & 255) < off) {
        const int u2 = tid + off;
        const float o = red[u2];
        const int oi = ridx[u2];
        if (o > red[tid] || (o == red[tid] && oi < ridx[tid])) { red[tid] = o; ridx[tid] = oi; }
      }
      __syncthreads();
    }
    if (tid < 4) {
      mxv[tid] = red[tid * 256];
      amv[tid] = ridx[tid * 256];
      tgv[tid] = target[(size_t)(b0 + tid) * Tn + t];
    }
    __syncthreads();
    red[tid] = expf(lg[tid] - mxv[tid >> 8]);
    __syncthreads();
    for (int off = 128; off; off >>= 1) {
      if ((tid & 255) < off) red[tid] += red[tid + off];
      __syncthreads();
    }
    if (tid < 4) {
      const int r = tid;
      lzv[r] = logf(red[r * 256]);
      tokb[r] = amv[r];
      if (amv[r] != tgv[r]) mfs[r] = 0;
      out[(size_t)(b0 + r) * Tn + t] = (float)amv[r];
    }
    __syncthreads();
    {
      const int r = tid >> 8, v = tid & 255;
      if (v == tgv[r]) llv[r] = -(lg[tid] - mxv[r] - lzv[r]) * (1.f / 1024.f);
    }
    __syncthreads();
    if (tid == 0) run_loss += llv[0] + llv[1] + llv[2] + llv[3];
    __syncthreads();
  }

  if (tid == 0) {
    atomicAdd(wsloss, run_loss);
    atomicAdd(wscorrect, mfs[0] + mfs[1] + mfs[2] + mfs[3]);
  }
}

// ============ Path A fallback: R5-verified decoder (uncoalesced weights) ========
__device__ __forceinline__ void gru_layer4(int j, const float* __restrict__ x,
                                           int xstride, int K,
                                           float* __restrict__ h,
                                           const float* __restrict__ Wih,
                                           const float* __restrict__ Whh,
                                           const float* __restrict__ bih,
                                           const float* __restrict__ bhh) {
  float ai0[4] = {}, ai1[4] = {}, ai2[4] = {};
  {
    const float4* w0 = (const float4*)(Wih + (size_t)j * K);
    const float4* w1 = (const float4*)(Wih + (size_t)(j + 512) * K);
    const float4* w2 = (const float4*)(Wih + (size_t)(j + 1024) * K);
    for (int i = 0; i < K / 4; ++i) {
      const float4 a = w0[i], b = w1[i], c = w2[i];
#pragma unroll
      for (int r = 0; r < 4; ++r) {
        const float4 xv = ((const float4*)(x + r * xstride))[i];
        fma4(ai0[r], a, xv); fma4(ai1[r], b, xv); fma4(ai2[r], c, xv);
      }
    }
  }
  float ah0[4] = {}, ah1[4] = {}, ah2[4] = {};
  {
    const float4* w0 = (const float4*)(Whh + (size_t)j * Hn);
    const float4* w1 = (const float4*)(Whh + (size_t)(j + 512) * Hn);
    const float4* w2 = (const float4*)(Whh + (size_t)(j + 1024) * Hn);
    for (int i = 0; i < Hn / 4; ++i) {
      const float4 a = w0[i], b = w1[i], c = w2[i];
#pragma unroll
      for (int r = 0; r < 4; ++r) {
        const float4 xv = ((const float4*)(h + r * Hn))[i];
        fma4(ah0[r], a, xv); fma4(ah1[r], b, xv); fma4(ah2[r], c, xv);
      }
    }
  }
  const float bi0 = bih[j], bi1 = bih[j + 512], bi2 = bih[j + 1024];
  const float bh0 = bhh[j], bh1 = bhh[j + 512], bh2 = bhh[j + 1024];
  float hn[4];
#pragma unroll
  for (int r = 0; r < 4; ++r) {
    const float ir = ai0[r] + bi0, iz = ai1[r] + bi1, in_ = ai2[r] + bi2;
    const float hr = ah0[r] + bh0, hz = ah1[r] + bh1, hnn = ah2[r] + bh2;
    const float rg = 1.f / (1.f + expf(-(ir + hr)));
    const float zg = 1.f / (1.f + expf(-(iz + hz)));
    const float ng = tanhf(in_ + rg * hnn);
    hn[r] = (1.f - zg) * ng + zg * h[r * Hn + j];
  }
  __syncthreads();
#pragma unroll
  for (int r = 0; r < 4; ++r) h[r * Hn + j] = hn[r];
  __syncthreads();
}

__global__ __launch_bounds__(512, 1) void decoder_r4(
    const float* __restrict__ state, const float* __restrict__ enc,
    const int* __restrict__ target, const float* __restrict__ emb,
    const float* __restrict__ Wa, const float* __restrict__ bWa,
    const float* __restrict__ Va, const float* __restrict__ bVa,
    const float* __restrict__ Wih0, const float* __restrict__ Whh0,
    const float* __restrict__ bih0, const float* __restrict__ bhh0,
    const float* __restrict__ Wih1, const float* __restrict__ Whh1,
    const float* __restrict__ bih1, const float* __restrict__ bhh1,
    const float* __restrict__ fcW, const float* __restrict__ fcb,
    const float* __restrict__ kproj, float* __restrict__ out,
    float* __restrict__ wsloss, int* __restrict__ wscorrect) {
  __shared__ float h0s[4 * Hn], h1s[4 * Hn], qps[4 * Hn], gins[4 * EHn], vas[Hn];
  __shared__ float red[1024], lg[1024];
  __shared__ int ridx[1024];
  __shared__ float wrs[4 * Sn];
  __shared__ float mxv[4], lzv[4], llv[4];
  __shared__ int amv[4], tgv[4], tokb[4], mfs[4];

  const int tid = threadIdx.x;
  const int b0 = blockIdx.x * 4;

  for (int i = tid; i < 4 * Hn; i += 512) {
    const int r = i >> 9, j = i & 511;
    h0s[i] = state[(size_t)(b0 + r) * Hn + j];
    h1s[i] = state[(size_t)(Bn + b0 + r) * Hn + j];
  }
  vas[tid] = Va[tid];
  if (tid < 4) { tokb[tid] = 1; mfs[tid] = 1; llv[tid] = 0.f; }
  __syncthreads();

  float run_loss = 0.f;

  for (int t = 0; t < Tn; ++t) {
    {
      const int h = tid;
      const float4* w4 = (const float4*)(Wa + (size_t)h * Hn);
      float a0 = 0.f, a1 = 0.f, a2 = 0.f, a3 = 0.f;
      for (int i = 0; i < Hn / 4; ++i) {
        const float4 w = w4[i];
        const float4 x0 = ((const float4*)(h1s))[i];
        const float4 x1 = ((const float4*)(h1s + Hn))[i];
        const float4 x2 = ((const float4*)(h1s + 2 * Hn))[i];
        const float4 x3 = ((const float4*)(h1s + 3 * Hn))[i];
        fma4(a0, w, x0); fma4(a1, w, x1); fma4(a2, w, x2); fma4(a3, w, x3);
      }
      const float bb = bWa[h];
      qps[h] = a0 + bb; qps[Hn + h] = a1 + bb;
      qps[2 * Hn + h] = a2 + bb; qps[3 * Hn + h] = a3 + bb;
    }
    __syncthreads();
    {
      const int p = tid >> 2, q = tid & 3;
      const int r = p >> 5, s = p & 31;
      const float4* kp4 = (const float4*)(kproj + ((size_t)s * Bn + (b0 + r)) * Hn);
      const float4* qp4 = (const float4*)(qps + r * Hn);
      const float4* va4 = (const float4*)vas;
      float partial = 0.f;
      for (int i = 0; i < 32; ++i) {
        const int f = q + (i << 2);
        const float4 k4 = kp4[f], q4 = qp4[f], v4 = va4[f];
        partial += v4.x * tanhf(q4.x + k4.x);
        partial += v4.y * tanhf(q4.y + k4.y);
        partial += v4.z * tanhf(q4.z + k4.z);
        partial += v4.w * tanhf(q4.w + k4.w);
      }
      red[tid] = partial;
    }
    __syncthreads();
    if (tid < 128) {
      float e = red[tid * 4] + red[tid * 4 + 1] + red[tid * 4 + 2] + red[tid * 4 + 3] + bVa[0];
      float m = e;
#pragma unroll
      for (int off = 16; off; off >>= 1) m = fmaxf(m, __shfl_xor(m, off));
      const float ex = expf(e - m);
      float ss = ex;
#pragma unroll
      for (int off = 16; off; off >>= 1) ss += __shfl_xor(ss, off);
      const float w = ex / ss;
      const int r = tid >> 5, s = tid & 31;
      wrs[tid] = w;
      out[(size_t)(Bn * Tn) + (size_t)t * (Bn * Sn) + (size_t)(b0 + r) * Sn + s] = w;
    }
    __syncthreads();
    {
      const int h = tid;
      float c0 = 0.f, c1 = 0.f, c2 = 0.f, c3 = 0.f;
      for (int s = 0; s < Sn; ++s) {
        const size_t base = ((size_t)s * Bn + b0) * Hn + h;
        c0 = fmaf(wrs[s], enc[base], c0);
        c1 = fmaf(wrs[32 + s], enc[base + Hn], c1);
        c2 = fmaf(wrs[64 + s], enc[base + 2 * Hn], c2);
        c3 = fmaf(wrs[96 + s], enc[base + 3 * Hn], c3);
      }
      gins[En + h] = c0; gins[EHn + En + h] = c1;
      gins[2 * EHn + En + h] = c2; gins[3 * EHn + En + h] = c3;
    }
    for (int i = tid; i < 4 * En; i += 512) {
      const int r = i >> 8, j = i & 255;
      gins[r * EHn + j] = fmaxf(emb[(size_t)tokb[r] * En + j], 0.f);
    }
    __syncthreads();
    gru_layer4(tid, gins, EHn, EHn, h0s, Wih0, Whh0, bih0, bhh0);
    gru_layer4(tid, h0s, Hn, Hn, h1s, Wih1, Whh1, bih1, bhh1);
    {
      const int v = tid & 255;
      const int rA = tid >> 8, rB = rA + 2;
      const float4* w4 = (const float4*)(fcW + (size_t)v * Hn);
      const float4* xA = (const float4*)(h1s + rA * Hn);
      const float4* xB = (const float4*)(h1s + rB * Hn);
      float aA = 0.f, aB = 0.f;
      for (int i = 0; i < Hn / 4; ++i) {
        const float4 w = w4[i];
        const float4 a = xA[i], b = xB[i];
        fma4(aA, w, a); fma4(aB, w, b);
      }
      const float fb = fcb[v];
      const float lA = aA + fb, lB = aB + fb;
      lg[rA * 256 + v] = lA; red[rA * 256 + v] = lA; ridx[rA * 256 + v] = v;
      lg[rB * 256 + v] = lB; red[rB * 256 + v] = lB; ridx[rB * 256 + v] = v;
    }
    __syncthreads();
    for (int off = 128; off; off >>= 1) {
#pragma unroll
      for (int half = 0; half < 2; ++half) {
        const int u = tid + half * 512;
        if ((u & 255) < off) {
          const int u2 = u + off;
          const float o = red[u2]; const int oi = ridx[u2];
          if (o > red[u] || (o == red[u] && oi < ridx[u])) { red[u] = o; ridx[u] = oi; }
        }
      }
      __syncthreads();
    }
    if (tid < 4) {
      mxv[tid] = red[tid * 256];
      amv[tid] = ridx[tid * 256];
      tgv[tid] = target[(size_t)(b0 + tid) * Tn + t];
    }
    __syncthreads();
#pragma unroll
    for (int half = 0; half < 2; ++half) {
      const int u = tid + half * 512;
      red[u] = expf(lg[u] - mxv[u >> 8]);
    }
    __syncthreads();
    for (int off = 128; off; off >>= 1) {
#pragma unroll
      for (int half = 0; half < 2; ++half) {
        const int u = tid + half * 512;
        if ((u & 255) < off) red[u] += red[u + off];
      }
      __syncthreads();
    }
    if (tid < 4) {
      const int r = tid;
      lzv[r] = logf(red[r * 256]);
      tokb[r] = amv[r];
      if (amv[r] != tgv[r]) mfs[r] = 0;
      out[(size_t)(b0 + r) * Tn + t] = (float)amv[r];
    }
    __syncthreads();
#pragma unroll
    for (int half = 0; half < 2; ++half) {
      const int u = tid + half * 512;
      const int r = u >> 8, v = u & 255;
      if (v == tgv[r]) llv[r] = -(lg[u] - mxv[r] - lzv[r]) * (1.f / 1024.f);
    }
    __syncthreads();
    if (tid == 0) run_loss += llv[0] + llv[1] + llv[2] + llv[3];
    __syncthreads();
  }

  if (tid == 0) {
    atomicAdd(wsloss, run_loss);
    atomicAdd(wscorrect, mfs[0] + mfs[1] + mfs[2] + mfs[3]);
  }
}

// ============ common epilogue ============
__global__ void ws_init(float* wsloss, int* wscorrect) {
  wsloss[0] = 0.f;
  wscorrect[0] = 0;
}

__global__ void finisher(const float* __restrict__ wsloss,
                         const int* __restrict__ wscorrect, float* __restrict__ out) {
  const size_t base = (size_t)Bn * Tn + (size_t)Tn * Bn * Sn;
  out[base] = wsloss[0];
  out[base + 1] = (float)wscorrect[0];
}

extern "C" void kernel_launch(void* const* d_in, const int* in_sizes, int n_in,
                              void* d_out, int out_size, void* d_ws, size_t ws_size,
                              hipStream_t stream) {
  const float* state = (const float*)d_in[0];
  const float* enc = (const float*)d_in[1];
  const int* target = (const int*)d_in[2];
  const float* emb = (const float*)d_in[3];
  const float* Wa = (const float*)d_in[4];
  const float* bWa = (const float*)d_in[5];
  const float* Ua = (const float*)d_in[6];
  const float* bUa = (const float*)d_in[7];
  const float* Va = (const float*)d_in[8];
  const float* bVa = (const float*)d_in[9];
  const float* Wih0 = (const float*)d_in[10];
  const float* Whh0 = (const float*)d_in[11];
  const float* bih0 = (const float*)d_in[12];
  const float* bhh0 = (const float*)d_in[13];
  const float* Wih1 = (const float*)d_in[14];
  const float* Whh1 = (const float*)d_in[15];
  const float* bih1 = (const float*)d_in[16];
  const float* bhh1 = (const float*)d_in[17];
  const float* fcW = (const float*)d_in[18];
  const float* fcb = (const float*)d_in[19];
  float* out = (float*)d_out;

  const size_t KPROJ_FLOATS = (size_t)Sn * Bn * Hn;  // 64 MB

  const size_t N0IH = (size_t)G3 * (EHn / 4);
  const size_t NHH = (size_t)G3 * (Hn / 4);
  const size_t NWA = (size_t)Hn * (Hn / 4);
  const size_t NFC = (size_t)Vn * (Hn / 4);
  const size_t WT_TOTAL = N0IH + 3 * NHH + NWA + NFC;  // 15 MB
  const size_t NEED_A2 = WT_TOTAL * 16 + KPROJ_FLOATS * 4 + 256;

  if (ws_size >= NEED_A2) {
    float4* W0ihT = (float4*)d_ws;
    float4* W0hhT = W0ihT + N0IH;
    float4* W1ihT = W0hhT + NHH;
    float4* W1hhT = W1ihT + NHH;
    float4* WaT = W1hhT + NHH;
    float4* fcWT = WaT + NWA;
    float* kproj = (float*)(fcWT + NFC);
    float* wsloss = kproj + KPROJ_FLOATS;
    int* wscorrect = (int*)(wsloss + 1);

    hipFuncSetAttribute((const void*)decoder_r4x,
                        hipFuncAttributeMaxDynamicSharedMemorySize, LDS_BYTES2);

    ws_init<<<1, 1, 0, stream>>>(wsloss, wscorrect);
    transpose_pack<<<(int)((N0IH + 255) / 256), 256, 0, stream>>>(Wih0, W0ihT, G3, EHn);
    transpose_pack<<<(int)((NHH + 255) / 256), 256, 0, stream>>>(Whh0, W0hhT, G3, Hn);
    transpose_pack<<<(int)((NHH + 255) / 256), 256, 0, stream>>>(Wih1, W1ihT, G3, Hn);
    transpose_pack<<<(int)((NHH + 255) / 256), 256, 0, stream>>>(Whh1, W1hhT, G3, Hn);
    transpose_pack<<<(int)((NWA + 255) / 256), 256, 0, stream>>>(Wa, WaT, Hn, Hn);
    transpose_pack<<<(int)((NFC + 255) / 256), 256, 0, stream>>>(fcW, fcWT, Vn, Hn);
    gemm_bias<<<dim3(Hn / 64, (Sn * Bn) / 64), 256, 0, stream>>>(
        enc, Ua, bUa, kproj, Sn * Bn, Hn, Hn);
    decoder_r4x<<<Bn / 4, 1024, LDS_BYTES2, stream>>>(
        state, enc, target, emb, WaT, bWa, Va, bVa, W0ihT, W0hhT, bih0, bhh0,
        W1ihT, W1hhT, bih1, bhh1, fcWT, fcb, kproj, out, wsloss, wscorrect);
    finisher<<<1, 1, 0, stream>>>(wsloss, wscorrect, out);
  } else {
    float* kproj = (float*)d_ws;
    float* wsloss = (float*)d_ws + KPROJ_FLOATS;
    int* wscorrect = (int*)((float*)d_ws + KPROJ_FLOATS + 1);
    ws_init<<<1, 1, 0, stream>>>(wsloss, wscorrect);
    gemm_bias<<<dim3(Hn / 64, (Sn * Bn) / 64), 256, 0, stream>>>(
        enc, Ua, bUa, kproj, Sn * Bn, Hn, Hn);
    decoder_r4<<<Bn / 4, 512, 0, stream>>>(
        state, enc, target, emb, Wa, bWa, Va, bVa, Wih0, Whh0, bih0, bhh0,
        Wih1, Whh1, bih1, bhh1, fcW, fcb, kproj, out, wsloss, wscorrect);
    finisher<<<1, 1, 0, stream>>>(wsloss, wscorrect, out);
  }
}

// Round 9
// 10320.993 us; speedup vs baseline: 5.5764x; 1.0521x over previous
//
#include <hip/hip_runtime.h>
#include <math.h>

#define Hn 512
#define En 256
#define Sn 32
#define Bn 1024
#define Tn 32
#define Vn 256
#define G3 1536
#define EHn 768

// fma4 as a FUNCTION, not a macro (R6 lesson: macro param `w` collides with `.w`).
__device__ __forceinline__ void fma4(float& acc, const float4 w, const float4 x) {
  acc = fmaf(w.x, x.x, acc);
  acc = fmaf(w.y, x.y, acc);
  acc = fmaf(w.z, x.z, acc);
  acc = fmaf(w.w, x.w, acc);
}

// ============ one-time weight transpose: W[gate][K] -> WT4[k4*G + g] ============
__global__ __launch_bounds__(256) void transpose_pack(const float* __restrict__ W,
                                                      float4* __restrict__ WT4,
                                                      int G, int K) {
  const int idx = blockIdx.x * blockDim.x + threadIdx.x;
  const int n = G * (K >> 2);
  if (idx >= n) return;
  const int k4 = idx / G, g = idx - k4 * G;
  WT4[idx] = *(const float4*)(W + (size_t)g * K + (k4 << 2));
}

// ============ kproj GEMM: C(M,N) = A(M,K) @ W(N,K)^T + bias ============
__global__ __launch_bounds__(256) void gemm_bias(const float* __restrict__ A,
                                                 const float* __restrict__ Wt,
                                                 const float* __restrict__ bias,
                                                 float* __restrict__ C,
                                                 int M, int N, int K) {
  __shared__ float As[16][68];
  __shared__ float Ws[16][68];
  const int bm = blockIdx.y * 64;
  const int bn = blockIdx.x * 64;
  const int tid = threadIdx.x;
  const int tx = tid & 15;
  const int ty = tid >> 4;
  const int kk = tid & 15;
  const int r0 = tid >> 4;
  float acc[4][4] = {};
  for (int k0 = 0; k0 < K; k0 += 16) {
#pragma unroll
    for (int i = 0; i < 4; ++i) {
      const int m = r0 + (i << 4);
      As[kk][m] = A[(size_t)(bm + m) * K + (k0 + kk)];
      Ws[kk][m] = Wt[(size_t)(bn + m) * K + (k0 + kk)];
    }
    __syncthreads();
#pragma unroll
    for (int k = 0; k < 16; ++k) {
      const float4 a4 = *(const float4*)&As[k][ty * 4];
      const float4 w4 = *(const float4*)&Ws[k][tx * 4];
      const float av[4] = {a4.x, a4.y, a4.z, a4.w};
      const float wv[4] = {w4.x, w4.y, w4.z, w4.w};
#pragma unroll
      for (int i = 0; i < 4; ++i)
#pragma unroll
        for (int j = 0; j < 4; ++j) acc[i][j] = fmaf(av[i], wv[j], acc[i][j]);
    }
    __syncthreads();
  }
#pragma unroll
  for (int i = 0; i < 4; ++i) {
    const size_t m = (size_t)bm + ty * 4 + i;
    float* crow = C + m * N + bn + tx * 4;
#pragma unroll
    for (int j = 0; j < 4; ++j) crow[j] = acc[i][j] + bias[bn + tx * 4 + j];
  }
}

// ==================== dynamic-LDS layout for the 1024-thread decoder ============
#define O_H0   0        // [4][512]
#define O_H1   2048
#define O_QP   4096
#define O_GIN  6144     // [4][768]
#define O_VA   9216     // [512]
#define O_WR   9728     // [4][32]
#define O_MX   9856     // float[4]
#define O_LZ   9860
#define O_LL   9864
#define O_AM   9868     // int[4]
#define O_TG   9872
#define O_TOK  9876
#define O_MF   9880
#define O_PRT  9888     // [16][1024] partials (SoA, conflict-free); aliases red/lg/ridx
#define LDS_FLOATS2 (O_PRT + 16 * 1024)   // 26272 floats = 105088 B
#define LDS_BYTES2 (LDS_FLOATS2 * 4)

// GRU layer with K split across thread pairs (tid, tid+512).
__device__ __forceinline__ void gru_block(
    int tid, const float4* __restrict__ WihT, int Kih,
    const float4* __restrict__ WhhT,
    const float* __restrict__ x, int xstride,  // LDS [4][xstride]
    float* __restrict__ h,                     // LDS [4][Hn]
    const float* __restrict__ bih, const float* __restrict__ bhh,
    float* __restrict__ prt) {
  const int jj = tid & 511;
  const int half = tid >> 9;
  float ar[4] = {}, az[4] = {}, ain[4] = {}, ahn[4] = {};
  {
    const int kc = (Kih >> 2) >> 1;
    const int k0 = half * kc;
    const float4* w0 = WihT + jj + (size_t)k0 * G3;
    const float4* w1 = WihT + jj + 512 + (size_t)k0 * G3;
    const float4* w2 = WihT + jj + 1024 + (size_t)k0 * G3;
    for (int k4 = 0; k4 < kc; ++k4) {
      const float4 a = *w0; w0 += G3;
      const float4 b = *w1; w1 += G3;
      const float4 c = *w2; w2 += G3;
#pragma unroll
      for (int r = 0; r < 4; ++r) {
        const float4 xv = ((const float4*)(x + r * xstride))[k0 + k4];
        fma4(ar[r], a, xv);
        fma4(az[r], b, xv);
        fma4(ain[r], c, xv);
      }
    }
  }
  {
    const int kc = (Hn >> 2) >> 1;
    const int k0 = half * kc;
    const float4* w0 = WhhT + jj + (size_t)k0 * G3;
    const float4* w1 = WhhT + jj + 512 + (size_t)k0 * G3;
    const float4* w2 = WhhT + jj + 1024 + (size_t)k0 * G3;
    for (int k4 = 0; k4 < kc; ++k4) {
      const float4 a = *w0; w0 += G3;
      const float4 b = *w1; w1 += G3;
      const float4 c = *w2; w2 += G3;
#pragma unroll
      for (int r = 0; r < 4; ++r) {
        const float4 xv = ((const float4*)(h + r * Hn))[k0 + k4];
        fma4(ar[r], a, xv);
        fma4(az[r], b, xv);
        fma4(ahn[r], c, xv);
      }
    }
  }
#pragma unroll
  for (int r = 0; r < 4; ++r) {
    prt[r * 1024 + tid] = ar[r];
    prt[(4 + r) * 1024 + tid] = az[r];
    prt[(8 + r) * 1024 + tid] = ain[r];
    prt[(12 + r) * 1024 + tid] = ahn[r];
  }
  __syncthreads();
  float hn[4];
  if (tid < 512) {
    const int j = tid;
    const float bir = bih[j], biz = bih[j + 512], bin = bih[j + 1024];
    const float bhr = bhh[j], bhz = bhh[j + 512], bhn = bhh[j + 1024];
#pragma unroll
    for (int r = 0; r < 4; ++r) {
      const float srr = prt[r * 1024 + j] + prt[r * 1024 + j + 512] + bir + bhr;
      const float szz = prt[(4 + r) * 1024 + j] + prt[(4 + r) * 1024 + j + 512] + biz + bhz;
      const float sin_ = prt[(8 + r) * 1024 + j] + prt[(8 + r) * 1024 + j + 512] + bin;
      const float shn = prt[(12 + r) * 1024 + j] + prt[(12 + r) * 1024 + j + 512] + bhn;
      const float rg = 1.f / (1.f + expf(-srr));
      const float zg = 1.f / (1.f + expf(-szz));
      const float ng = tanhf(sin_ + rg * shn);
      hn[r] = (1.f - zg) * ng + zg * h[r * Hn + j];
    }
  }
  __syncthreads();
  if (tid < 512) {
#pragma unroll
    for (int r = 0; r < 4; ++r) h[r * Hn + tid] = hn[r];
  }
  __syncthreads();
}

// ============ Path A2: R=4, 1024-thread persistent decoder (K-split) ============
// NOTE: plain __launch_bounds__(1024): backend must keep the 1024-block
// launchable -> VGPR <= 128. R8's (1024,4) capped VGPR at 64 -> 2.8 GB of
// scratch spill traffic per dispatch (WRITE_SIZE counter) and no speedup.
__global__ __launch_bounds__(1024) void decoder_r4x(
    const float* __restrict__ state, const float* __restrict__ enc,
    const int* __restrict__ target, const float* __restrict__ emb,
    const float4* __restrict__ WaT, const float* __restrict__ bWa,
    const float* __restrict__ Va, const float* __restrict__ bVa,
    const float4* __restrict__ W0ihT, const float4* __restrict__ W0hhT,
    const float* __restrict__ bih0, const float* __restrict__ bhh0,
    const float4* __restrict__ W1ihT, const float4* __restrict__ W1hhT,
    const float* __restrict__ bih1, const float* __restrict__ bhh1,
    const float4* __restrict__ fcWT, const float* __restrict__ fcb,
    const float* __restrict__ kproj, float* __restrict__ out,
    float* __restrict__ wsloss, int* __restrict__ wscorrect) {
  extern __shared__ float L[];
  float* h0s = L + O_H0;
  float* h1s = L + O_H1;
  float* qps = L + O_QP;
  float* gins = L + O_GIN;
  float* vas = L + O_VA;
  float* wrs = L + O_WR;
  float* mxv = L + O_MX;
  float* lzv = L + O_LZ;
  float* llv = L + O_LL;
  int* amv = (int*)(L + O_AM);
  int* tgv = (int*)(L + O_TG);
  int* tokb = (int*)(L + O_TOK);
  int* mfs = (int*)(L + O_MF);
  float* prt = L + O_PRT;
  float* red = prt;            // 1024 (fc phase only)
  float* lg = prt + 1024;      // 1024
  int* ridx = (int*)(prt + 2048);

  const int tid = threadIdx.x;
  const int b0 = blockIdx.x * 4;

  for (int i = tid; i < 4 * Hn; i += 1024) {
    const int r = i >> 9, j = i & 511;
    h0s[i] = state[(size_t)(b0 + r) * Hn + j];
    h1s[i] = state[(size_t)(Bn + b0 + r) * Hn + j];
  }
  if (tid < 512) vas[tid] = Va[tid];
  if (tid < 4) { tokb[tid] = 1; mfs[tid] = 1; llv[tid] = 0.f; }
  __syncthreads();

  float run_loss = 0.f;  // tid 0 only

  for (int t = 0; t < Tn; ++t) {
    // ---- qp = h1 @ Wa^T + bWa, K split across thread pairs ----
    {
      const int hh = tid & 511, half = tid >> 9;
      const int kc = (Hn >> 2) >> 1;
      const int k0 = half * kc;
      const float4* wp = WaT + hh + (size_t)k0 * Hn;
      float a0 = 0.f, a1 = 0.f, a2 = 0.f, a3 = 0.f;
      for (int k4 = 0; k4 < kc; ++k4) {
        const float4 w = *wp; wp += Hn;
        const float4 x0 = ((const float4*)(h1s))[k0 + k4];
        const float4 x1 = ((const float4*)(h1s + Hn))[k0 + k4];
        const float4 x2 = ((const float4*)(h1s + 2 * Hn))[k0 + k4];
        const float4 x3 = ((const float4*)(h1s + 3 * Hn))[k0 + k4];
        fma4(a0, w, x0); fma4(a1, w, x1); fma4(a2, w, x2); fma4(a3, w, x3);
      }
      prt[tid] = a0;
      prt[1024 + tid] = a1;
      prt[2048 + tid] = a2;
      prt[3072 + tid] = a3;
    }
    __syncthreads();
    if (tid < 512) {
      const float bb = bWa[tid];
      qps[tid] = prt[tid] + prt[tid + 512] + bb;
      qps[Hn + tid] = prt[1024 + tid] + prt[1024 + tid + 512] + bb;
      qps[2 * Hn + tid] = prt[2048 + tid] + prt[2048 + tid + 512] + bb;
      qps[3 * Hn + tid] = prt[3072 + tid] + prt[3072 + tid + 512] + bb;
    }
    __syncthreads();
    // ---- e: 8 threads per (r,s) pair; kproj streamed from global ----
    {
      const int p = tid >> 3, q = tid & 7;  // p = r*32+s
      const int r = p >> 5, s = p & 31;
      const float4* kp4 = (const float4*)(kproj + ((size_t)s * Bn + (b0 + r)) * Hn);
      const float4* qp4 = (const float4*)(qps + r * Hn);
      const float4* va4 = (const float4*)vas;
      float partial = 0.f;
      for (int i = 0; i < 16; ++i) {
        const int f = q + (i << 3);
        const float4 k4 = kp4[f], q4 = qp4[f], v4 = va4[f];
        partial += v4.x * tanhf(q4.x + k4.x);
        partial += v4.y * tanhf(q4.y + k4.y);
        partial += v4.z * tanhf(q4.z + k4.z);
        partial += v4.w * tanhf(q4.w + k4.w);
      }
      prt[tid] = partial;
    }
    __syncthreads();
    if (tid < 128) {
      float e = prt[tid * 8] + prt[tid * 8 + 1] + prt[tid * 8 + 2] + prt[tid * 8 + 3] +
                prt[tid * 8 + 4] + prt[tid * 8 + 5] + prt[tid * 8 + 6] + prt[tid * 8 + 7] +
                bVa[0];
      float m = e;
#pragma unroll
      for (int off = 16; off; off >>= 1) m = fmaxf(m, __shfl_xor(m, off));
      const float ex = expf(e - m);
      float ss = ex;
#pragma unroll
      for (int off = 16; off; off >>= 1) ss += __shfl_xor(ss, off);
      const float w = ex / ss;
      const int r = tid >> 5, s = tid & 31;
      wrs[tid] = w;
      out[(size_t)(Bn * Tn) + (size_t)t * (Bn * Sn) + (size_t)(b0 + r) * Sn + s] = w;
    }
    __syncthreads();
    // ---- context (2 rows per thread) + relu(emb[tok]) -> gin ----
    {
      const int h = tid & 511, rp = tid >> 9;  // rows 2rp, 2rp+1
      float c0 = 0.f, c1 = 0.f;
      const float* w0 = wrs + (2 * rp) * 32;
      const float* w1 = wrs + (2 * rp + 1) * 32;
      for (int s = 0; s < Sn; ++s) {
        const size_t base = ((size_t)s * Bn + b0 + 2 * rp) * Hn + h;
        c0 = fmaf(w0[s], enc[base], c0);
        c1 = fmaf(w1[s], enc[base + Hn], c1);
      }
      gins[(2 * rp) * EHn + En + h] = c0;
      gins[(2 * rp + 1) * EHn + En + h] = c1;
    }
    {
      const int r = tid >> 8, j = tid & 255;
      gins[r * EHn + j] = fmaxf(emb[(size_t)tokb[r] * En + j], 0.f);
    }
    __syncthreads();
    // ---- GRU layers (K-split) ----
    gru_block(tid, W0ihT, EHn, W0hhT, gins, EHn, h0s, bih0, bhh0, prt);
    gru_block(tid, W1ihT, Hn, W1hhT, h0s, Hn, h1s, bih1, bhh1, prt);
    // ---- fc: one (v, row) per thread; coalesced fcWT reads ----
    {
      const int v = tid & 255, r = tid >> 8;
      const float4* wp = fcWT + v;
      const float4* xr = (const float4*)(h1s + r * Hn);
      float acc = 0.f;
      for (int k4 = 0; k4 < (Hn >> 2); ++k4) {
        const float4 w = *wp; wp += Vn;
        fma4(acc, w, xr[k4]);
      }
      const float l = acc + fcb[v];
      lg[tid] = l;
      red[tid] = l;
      ridx[tid] = v;
    }
    __syncthreads();
    // argmax (first-max tie-break) per 256-segment
    for (int off = 128; off; off >>= 1) {
      if ((tid & 255) < off) {
        const int u2 = tid + off;
        const float o = red[u2];
        const int oi = ridx[u2];
        if (o > red[tid] || (o == red[tid] && oi < ridx[tid])) { red[tid] = o; ridx[tid] = oi; }
      }
      __syncthreads();
    }
    if (tid < 4) {
      mxv[tid] = red[tid * 256];
      amv[tid] = ridx[tid * 256];
      tgv[tid] = target[(size_t)(b0 + tid) * Tn + t];
    }
    __syncthreads();
    red[tid] = expf(lg[tid] - mxv[tid >> 8]);
    __syncthreads();
    for (int off = 128; off; off >>= 1) {
      if ((tid & 255) < off) red[tid] += red[tid + off];
      __syncthreads();
    }
    if (tid < 4) {
      const int r = tid;
      lzv[r] = logf(red[r * 256]);
      tokb[r] = amv[r];
      if (amv[r] != tgv[r]) mfs[r] = 0;
      out[(size_t)(b0 + r) * Tn + t] = (float)amv[r];
    }
    __syncthreads();
    {
      const int r = tid >> 8, v = tid & 255;
      if (v == tgv[r]) llv[r] = -(lg[tid] - mxv[r] - lzv[r]) * (1.f / 1024.f);
    }
    __syncthreads();
    if (tid == 0) run_loss += llv[0] + llv[1] + llv[2] + llv[3];
    __syncthreads();
  }

  if (tid == 0) {
    atomicAdd(wsloss, run_loss);
    atomicAdd(wscorrect, mfs[0] + mfs[1] + mfs[2] + mfs[3]);
  }
}

// ============ Path A fallback: R5-verified decoder (uncoalesced weights) ========
__device__ __forceinline__ void gru_layer4(int j, const float* __restrict__ x,
                                           int xstride, int K,
                                           float* __restrict__ h,
                                           const float* __restrict__ Wih,
                                           const float* __restrict__ Whh,
                                           const float* __restrict__ bih,
                                           const float* __restrict__ bhh) {
  float ai0[4] = {}, ai1[4] = {}, ai2[4] = {};
  {
    const float4* w0 = (const float4*)(Wih + (size_t)j * K);
    const float4* w1 = (const float4*)(Wih + (size_t)(j + 512) * K);
    const float4* w2 = (const float4*)(Wih + (size_t)(j + 1024) * K);
    for (int i = 0; i < K / 4; ++i) {
      const float4 a = w0[i], b = w1[i], c = w2[i];
#pragma unroll
      for (int r = 0; r < 4; ++r) {
        const float4 xv = ((const float4*)(x + r * xstride))[i];
        fma4(ai0[r], a, xv); fma4(ai1[r], b, xv); fma4(ai2[r], c, xv);
      }
    }
  }
  float ah0[4] = {}, ah1[4] = {}, ah2[4] = {};
  {
    const float4* w0 = (const float4*)(Whh + (size_t)j * Hn);
    const float4* w1 = (const float4*)(Whh + (size_t)(j + 512) * Hn);
    const float4* w2 = (const float4*)(Whh + (size_t)(j + 1024) * Hn);
    for (int i = 0; i < Hn / 4; ++i) {
      const float4 a = w0[i], b = w1[i], c = w2[i];
#pragma unroll
      for (int r = 0; r < 4; ++r) {
        const float4 xv = ((const float4*)(h + r * Hn))[i];
        fma4(ah0[r], a, xv); fma4(ah1[r], b, xv); fma4(ah2[r], c, xv);
      }
    }
  }
  const float bi0 = bih[j], bi1 = bih[j + 512], bi2 = bih[j + 1024];
  const float bh0 = bhh[j], bh1 = bhh[j + 512], bh2 = bhh[j + 1024];
  float hn[4];
#pragma unroll
  for (int r = 0; r < 4; ++r) {
    const float ir = ai0[r] + bi0, iz = ai1[r] + bi1, in_ = ai2[r] + bi2;
    const float hr = ah0[r] + bh0, hz = ah1[r] + bh1, hnn = ah2[r] + bh2;
    const float rg = 1.f / (1.f + expf(-(ir + hr)));
    const float zg = 1.f / (1.f + expf(-(iz + hz)));
    const float ng = tanhf(in_ + rg * hnn);
    hn[r] = (1.f - zg) * ng + zg * h[r * Hn + j];
  }
  __syncthreads();
#pragma unroll
  for (int r = 0; r < 4; ++r) h[r * Hn + j] = hn[r];
  __syncthreads();
}

__global__ __launch_bounds__(512, 1) void decoder_r4(
    const float* __restrict__ state, const float* __restrict__ enc,
    const int* __restrict__ target, const float* __restrict__ emb,
    const float* __restrict__ Wa, const float* __restrict__ bWa,
    const float* __restrict__ Va, const float* __restrict__ bVa,
    const float* __restrict__ Wih0, const float* __restrict__ Whh0,
    const float* __restrict__ bih0, const float* __restrict__ bhh0,
    const float* __restrict__ Wih1, const float* __restrict__ Whh1,
    const float* __restrict__ bih1, const float* __restrict__ bhh1,
    const float* __restrict__ fcW, const float* __restrict__ fcb,
    const float* __restrict__ kproj, float* __restrict__ out,
    float* __restrict__ wsloss, int* __restrict__ wscorrect) {
  __shared__ float h0s[4 * Hn], h1s[4 * Hn], qps[4 * Hn], gins[4 * EHn], vas[Hn];
  __shared__ float red[1024], lg[1024];
  __shared__ int ridx[1024];
  __shared__ float wrs[4 * Sn];
  __shared__ float mxv[4], lzv[4], llv[4];
  __shared__ int amv[4], tgv[4], tokb[4], mfs[4];

  const int tid = threadIdx.x;
  const int b0 = blockIdx.x * 4;

  for (int i = tid; i < 4 * Hn; i += 512) {
    const int r = i >> 9, j = i & 511;
    h0s[i] = state[(size_t)(b0 + r) * Hn + j];
    h1s[i] = state[(size_t)(Bn + b0 + r) * Hn + j];
  }
  vas[tid] = Va[tid];
  if (tid < 4) { tokb[tid] = 1; mfs[tid] = 1; llv[tid] = 0.f; }
  __syncthreads();

  float run_loss = 0.f;

  for (int t = 0; t < Tn; ++t) {
    {
      const int h = tid;
      const float4* w4 = (const float4*)(Wa + (size_t)h * Hn);
      float a0 = 0.f, a1 = 0.f, a2 = 0.f, a3 = 0.f;
      for (int i = 0; i < Hn / 4; ++i) {
        const float4 w = w4[i];
        const float4 x0 = ((const float4*)(h1s))[i];
        const float4 x1 = ((const float4*)(h1s + Hn))[i];
        const float4 x2 = ((const float4*)(h1s + 2 * Hn))[i];
        const float4 x3 = ((const float4*)(h1s + 3 * Hn))[i];
        fma4(a0, w, x0); fma4(a1, w, x1); fma4(a2, w, x2); fma4(a3, w, x3);
      }
      const float bb = bWa[h];
      qps[h] = a0 + bb; qps[Hn + h] = a1 + bb;
      qps[2 * Hn + h] = a2 + bb; qps[3 * Hn + h] = a3 + bb;
    }
    __syncthreads();
    {
      const int p = tid >> 2, q = tid & 3;
      const int r = p >> 5, s = p & 31;
      const float4* kp4 = (const float4*)(kproj + ((size_t)s * Bn + (b0 + r)) * Hn);
      const float4* qp4 = (const float4*)(qps + r * Hn);
      const float4* va4 = (const float4*)vas;
      float partial = 0.f;
      for (int i = 0; i < 32; ++i) {
        const int f = q + (i << 2);
        const float4 k4 = kp4[f], q4 = qp4[f], v4 = va4[f];
        partial += v4.x * tanhf(q4.x + k4.x);
        partial += v4.y * tanhf(q4.y + k4.y);
        partial += v4.z * tanhf(q4.z + k4.z);
        partial += v4.w * tanhf(q4.w + k4.w);
      }
      red[tid] = partial;
    }
    __syncthreads();
    if (tid < 128) {
      float e = red[tid * 4] + red[tid * 4 + 1] + red[tid * 4 + 2] + red[tid * 4 + 3] + bVa[0];
      float m = e;
#pragma unroll
      for (int off = 16; off; off >>= 1) m = fmaxf(m, __shfl_xor(m, off));
      const float ex = expf(e - m);
      float ss = ex;
#pragma unroll
      for (int off = 16; off; off >>= 1) ss += __shfl_xor(ss, off);
      const float w = ex / ss;
      const int r = tid >> 5, s = tid & 31;
      wrs[tid] = w;
      out[(size_t)(Bn * Tn) + (size_t)t * (Bn * Sn) + (size_t)(b0 + r) * Sn + s] = w;
    }
    __syncthreads();
    {
      const int h = tid;
      float c0 = 0.f, c1 = 0.f, c2 = 0.f, c3 = 0.f;
      for (int s = 0; s < Sn; ++s) {
        const size_t base = ((size_t)s * Bn + b0) * Hn + h;
        c0 = fmaf(wrs[s], enc[base], c0);
        c1 = fmaf(wrs[32 + s], enc[base + Hn], c1);
        c2 = fmaf(wrs[64 + s], enc[base + 2 * Hn], c2);
        c3 = fmaf(wrs[96 + s], enc[base + 3 * Hn], c3);
      }
      gins[En + h] = c0; gins[EHn + En + h] = c1;
      gins[2 * EHn + En + h] = c2; gins[3 * EHn + En + h] = c3;
    }
    for (int i = tid; i < 4 * En; i += 512) {
      const int r = i >> 8, j = i & 255;
      gins[r * EHn + j] = fmaxf(emb[(size_t)tokb[r] * En + j], 0.f);
    }
    __syncthreads();
    gru_layer4(tid, gins, EHn, EHn, h0s, Wih0, Whh0, bih0, bhh0);
    gru_layer4(tid, h0s, Hn, Hn, h1s, Wih1, Whh1, bih1, bhh1);
    {
      const int v = tid & 255;
      const int rA = tid >> 8, rB = rA + 2;
      const float4* w4 = (const float4*)(fcW + (size_t)v * Hn);
      const float4* xA = (const float4*)(h1s + rA * Hn);
      const float4* xB = (const float4*)(h1s + rB * Hn);
      float aA = 0.f, aB = 0.f;
      for (int i = 0; i < Hn / 4; ++i) {
        const float4 w = w4[i];
        const float4 a = xA[i], b = xB[i];
        fma4(aA, w, a); fma4(aB, w, b);
      }
      const float fb = fcb[v];
      const float lA = aA + fb, lB = aB + fb;
      lg[rA * 256 + v] = lA; red[rA * 256 + v] = lA; ridx[rA * 256 + v] = v;
      lg[rB * 256 + v] = lB; red[rB * 256 + v] = lB; ridx[rB * 256 + v] = v;
    }
    __syncthreads();
    for (int off = 128; off; off >>= 1) {
#pragma unroll
      for (int half = 0; half < 2; ++half) {
        const int u = tid + half * 512;
        if ((u & 255) < off) {
          const int u2 = u + off;
          const float o = red[u2]; const int oi = ridx[u2];
          if (o > red[u] || (o == red[u] && oi < ridx[u])) { red[u] = o; ridx[u] = oi; }
        }
      }
      __syncthreads();
    }
    if (tid < 4) {
      mxv[tid] = red[tid * 256];
      amv[tid] = ridx[tid * 256];
      tgv[tid] = target[(size_t)(b0 + tid) * Tn + t];
    }
    __syncthreads();
#pragma unroll
    for (int half = 0; half < 2; ++half) {
      const int u = tid + half * 512;
      red[u] = expf(lg[u] - mxv[u >> 8]);
    }
    __syncthreads();
    for (int off = 128; off; off >>= 1) {
#pragma unroll
      for (int half = 0; half < 2; ++half) {
        const int u = tid + half * 512;
        if ((u & 255) < off) red[u] += red[u + off];
      }
      __syncthreads();
    }
    if (tid < 4) {
      const int r = tid;
      lzv[r] = logf(red[r * 256]);
      tokb[r] = amv[r];
      if (amv[r] != tgv[r]) mfs[r] = 0;
      out[(size_t)(b0 + r) * Tn + t] = (float)amv[r];
    }
    __syncthreads();
#pragma unroll
    for (int half = 0; half < 2; ++half) {
      const int u = tid + half * 512;
      const int r = u >> 8, v = u & 255;
      if (v == tgv[r]) llv[r] = -(lg[u] - mxv[r] - lzv[r]) * (1.f / 1024.f);
    }
    __syncthreads();
    if (tid == 0) run_loss += llv[0] + llv[1] + llv[2] + llv[3];
    __syncthreads();
  }

  if (tid == 0) {
    atomicAdd(wsloss, run_loss);
    atomicAdd(wscorrect, mfs[0] + mfs[1] + mfs[2] + mfs[3]);
  }
}

// ============ common epilogue ============
__global__ void ws_init(float* wsloss, int* wscorrect) {
  wsloss[0] = 0.f;
  wscorrect[0] = 0;
}

__global__ void finisher(const float* __restrict__ wsloss,
                         const int* __restrict__ wscorrect, float* __restrict__ out) {
  const size_t base = (size_t)Bn * Tn + (size_t)Tn * Bn * Sn;
  out[base] = wsloss[0];
  out[base + 1] = (float)wscorrect[0];
}

extern "C" void kernel_launch(void* const* d_in, const int* in_sizes, int n_in,
                              void* d_out, int out_size, void* d_ws, size_t ws_size,
                              hipStream_t stream) {
  const float* state = (const float*)d_in[0];
  const float* enc = (const float*)d_in[1];
  const int* target = (const int*)d_in[2];
  const float* emb = (const float*)d_in[3];
  const float* Wa = (const float*)d_in[4];
  const float* bWa = (const float*)d_in[5];
  const float* Ua = (const float*)d_in[6];
  const float* bUa = (const float*)d_in[7];
  const float* Va = (const float*)d_in[8];
  const float* bVa = (const float*)d_in[9];
  const float* Wih0 = (const float*)d_in[10];
  const float* Whh0 = (const float*)d_in[11];
  const float* bih0 = (const float*)d_in[12];
  const float* bhh0 = (const float*)d_in[13];
  const float* Wih1 = (const float*)d_in[14];
  const float* Whh1 = (const float*)d_in[15];
  const float* bih1 = (const float*)d_in[16];
  const float* bhh1 = (const float*)d_in[17];
  const float* fcW = (const float*)d_in[18];
  const float* fcb = (const float*)d_in[19];
  float* out = (float*)d_out;

  const size_t KPROJ_FLOATS = (size_t)Sn * Bn * Hn;  // 64 MB

  const size_t N0IH = (size_t)G3 * (EHn / 4);
  const size_t NHH = (size_t)G3 * (Hn / 4);
  const size_t NWA = (size_t)Hn * (Hn / 4);
  const size_t NFC = (size_t)Vn * (Hn / 4);
  const size_t WT_TOTAL = N0IH + 3 * NHH + NWA + NFC;  // 15 MB
  const size_t NEED_A2 = WT_TOTAL * 16 + KPROJ_FLOATS * 4 + 256;

  if (ws_size >= NEED_A2) {
    float4* W0ihT = (float4*)d_ws;
    float4* W0hhT = W0ihT + N0IH;
    float4* W1ihT = W0hhT + NHH;
    float4* W1hhT = W1ihT + NHH;
    float4* WaT = W1hhT + NHH;
    float4* fcWT = WaT + NWA;
    float* kproj = (float*)(fcWT + NFC);
    float* wsloss = kproj + KPROJ_FLOATS;
    int* wscorrect = (int*)(wsloss + 1);

    hipFuncSetAttribute((const void*)decoder_r4x,
                        hipFuncAttributeMaxDynamicSharedMemorySize, LDS_BYTES2);

    ws_init<<<1, 1, 0, stream>>>(wsloss, wscorrect);
    transpose_pack<<<(int)((N0IH + 255) / 256), 256, 0, stream>>>(Wih0, W0ihT, G3, EHn);
    transpose_pack<<<(int)((NHH + 255) / 256), 256, 0, stream>>>(Whh0, W0hhT, G3, Hn);
    transpose_pack<<<(int)((NHH + 255) / 256), 256, 0, stream>>>(Wih1, W1ihT, G3, Hn);
    transpose_pack<<<(int)((NHH + 255) / 256), 256, 0, stream>>>(Whh1, W1hhT, G3, Hn);
    transpose_pack<<<(int)((NWA + 255) / 256), 256, 0, stream>>>(Wa, WaT, Hn, Hn);
    transpose_pack<<<(int)((NFC + 255) / 256), 256, 0, stream>>>(fcW, fcWT, Vn, Hn);
    gemm_bias<<<dim3(Hn / 64, (Sn * Bn) / 64), 256, 0, stream>>>(
        enc, Ua, bUa, kproj, Sn * Bn, Hn, Hn);
    decoder_r4x<<<Bn / 4, 1024, LDS_BYTES2, stream>>>(
        state, enc, target, emb, WaT, bWa, Va, bVa, W0ihT, W0hhT, bih0, bhh0,
        W1ihT, W1hhT, bih1, bhh1, fcWT, fcb, kproj, out, wsloss, wscorrect);
    finisher<<<1, 1, 0, stream>>>(wsloss, wscorrect, out);
  } else {
    float* kproj = (float*)d_ws;
    float* wsloss = (float*)d_ws + KPROJ_FLOATS;
    int* wscorrect = (int*)((float*)d_ws + KPROJ_FLOATS + 1);
    ws_init<<<1, 1, 0, stream>>>(wsloss, wscorrect);
    gemm_bias<<<dim3(Hn / 64, (Sn * Bn) / 64), 256, 0, stream>>>(
        enc, Ua, bUa, kproj, Sn * Bn, Hn, Hn);
    decoder_r4<<<Bn / 4, 512, 0, stream>>>(
        state, enc, target, emb, Wa, bWa, Va, bVa, Wih0, Whh0, bih0, bhh0,
        Wih1, Whh1, bih1, bhh1, fcW, fcb, kproj, out, wsloss, wscorrect);
    finisher<<<1, 1, 0, stream>>>(wsloss, wscorrect, out);
  }
}